// Round 7
// baseline (272.678 us; speedup 1.0000x reference)
//
#include <hip/hip_runtime.h>

typedef unsigned int u32;
typedef _Float16 f16;
typedef _Float16 f16x8 __attribute__((ext_vector_type(8)));
typedef _Float16 f16x4 __attribute__((ext_vector_type(4)));
typedef float f32x4 __attribute__((ext_vector_type(4)));
typedef _Float16 __attribute__((address_space(3))) lf16;

#define LOG2E 1.4426950408889634f

__device__ __forceinline__ void gl_lds16(const void* g, void* l) {
  __builtin_amdgcn_global_load_lds(
      (const __attribute__((address_space(1))) u32*)g,
      (__attribute__((address_space(3))) u32*)l, 16, 0, 0);
}

__device__ __forceinline__ f32x4 mfma16(f16x8 a, f16x8 b, f32x4 c) {
  return __builtin_amdgcn_mfma_f32_16x16x32_f16(a, b, c, 0, 0, 0);
}

// inline-asm LDS read: compiler cannot see the memory op -> cannot insert
// conservative vmcnt(0) drains against outstanding global_load_lds (rule #18:
// we supply the lgkmcnt(0)+sched_barrier fence ourselves).
__device__ __forceinline__ f16x8 ldsr(const f16* p) {
  f16x8 r;
  asm volatile("ds_read_b128 %0, %1" : "=v"(r) : "v"((const lf16*)p));
  return r;
}

// ---------------- fp32 -> fp16 convert ----------------
__global__ void k_cvt(const float* __restrict__ in, f16* __restrict__ out, int n4) {
  int stride = gridDim.x * blockDim.x;
  for (int i = blockIdx.x * blockDim.x + threadIdx.x; i < n4; i += stride) {
    f32x4 v = *(const f32x4*)(in + (size_t)i * 4);
    f16x4 o;
    o[0] = (f16)v[0]; o[1] = (f16)v[1]; o[2] = (f16)v[2]; o[3] = (f16)v[3];
    *(f16x4*)(out + (size_t)i * 4) = o;
  }
}

// ------------- transpose + convert -------------
__global__ void k_tconv(const float* __restrict__ in, f16* __restrict__ out, int R, int C) {
  __shared__ f16 tile[32][33];
  int c0 = blockIdx.x * 32, r0 = blockIdx.y * 32;
  int tx = threadIdx.x, ty = threadIdx.y;
#pragma unroll
  for (int i = ty; i < 32; i += 8)
    tile[i][tx] = (f16)in[(size_t)(r0 + i) * C + c0 + tx];
  __syncthreads();
#pragma unroll
  for (int i = ty; i < 32; i += 8)
    out[(size_t)(c0 + i) * R + r0 + tx] = tile[tx][i];
}

// ================= fat-wave core, ASM LDS reads (experiment) =================
__device__ __forceinline__ void gemm_fatA(
    const f16* __restrict__ A, const f16* __restrict__ Bt,
    int bm, int bn, f16* SM, int w, int lane, f32x4 (&acc)[8][4]) {
  constexpr int KT = 32;
  const int g = lane >> 4, rl = lane & 15;
  const int l4 = lane >> 2, ls = lane & 3;
  const int sslot = ls ^ ((l4 >> 1) & 3);

  const f16* aS = A + (size_t)(bm + w * 32 + l4) * 1024 + sslot * 8;
  const f16* bS = Bt + (size_t)(bn + w * 16 + l4) * 1024 + sslot * 8;
  f16* aD = SM + w * 1024;
  f16* bD = SM + 4096 + w * 512;

#define ASTG0(b, kt) do { \
    gl_lds16(aS + (kt) * 32,          aD + (b) * 12288); \
    gl_lds16(aS + 16384 + (kt) * 32,  aD + (b) * 12288 + 512); \
    gl_lds16(bS + (kt) * 32,          bD + (b) * 12288); } while (0)
#define ASTG1(b, kt) do { \
    gl_lds16(bS + 65536 + (kt) * 32,  bD + (b) * 12288 + 2048); \
    gl_lds16(bS + 131072 + (kt) * 32, bD + (b) * 12288 + 4096); \
    gl_lds16(bS + 196608 + (kt) * 32, bD + (b) * 12288 + 6144); } while (0)

  ASTG0(0, 0); ASTG1(0, 0);
  ASTG0(1, 1); ASTG1(1, 1);
  asm volatile("s_waitcnt vmcnt(6)" ::: "memory");
  __builtin_amdgcn_s_barrier();

  const int ro = rl * 32 + ((g ^ ((rl >> 1) & 3)) * 8);

  int c = 0, cs = 2;
#pragma unroll 1
  for (int kt = 0; kt < KT; ++kt) {
    const f16* SMc = SM + c * 12288;
    const bool stg = (kt + 2 < KT);
    f16x8 bf[4], af[4];

    // ---------- phase 0: M rows 0..63 ----------
    {
#pragma unroll
      for (int j = 0; j < 4; ++j)
        bf[j] = ldsr(SMc + 4096 + w * 2048 + j * 512 + ro);
#pragma unroll
      for (int mi = 0; mi < 4; ++mi)
        af[mi] = ldsr(SMc + mi * 512 + ro);
      if (stg) ASTG0(cs, kt + 2);
      __builtin_amdgcn_s_barrier();
      asm volatile("s_waitcnt lgkmcnt(0)");
      __builtin_amdgcn_sched_barrier(0);
      __builtin_amdgcn_s_setprio(1);
#pragma unroll
      for (int mi = 0; mi < 4; ++mi)
#pragma unroll
        for (int j = 0; j < 4; ++j)
          acc[mi][j] = mfma16(af[mi], bf[j], acc[mi][j]);
      __builtin_amdgcn_s_setprio(0);
      __builtin_amdgcn_sched_barrier(0);
      __builtin_amdgcn_s_barrier();
    }

    // ---------- phase 1: M rows 64..127 ----------
    {
#pragma unroll
      for (int mi = 0; mi < 4; ++mi)
        af[mi] = ldsr(SMc + (4 + mi) * 512 + ro);
      if (stg) ASTG1(cs, kt + 2);
      __builtin_amdgcn_s_barrier();
      asm volatile("s_waitcnt lgkmcnt(0)");
      __builtin_amdgcn_sched_barrier(0);
      __builtin_amdgcn_s_setprio(1);
#pragma unroll
      for (int mi = 0; mi < 4; ++mi)
#pragma unroll
        for (int j = 0; j < 4; ++j)
          acc[4 + mi][j] = mfma16(af[mi], bf[j], acc[4 + mi][j]);
      __builtin_amdgcn_s_setprio(0);
      __builtin_amdgcn_sched_barrier(0);
      if (kt + 2 < KT)      { asm volatile("s_waitcnt vmcnt(6)" ::: "memory"); }
      else if (kt + 1 < KT) { asm volatile("s_waitcnt vmcnt(0)" ::: "memory"); }
      __builtin_amdgcn_s_barrier();
      __builtin_amdgcn_sched_barrier(0);
    }

    c = (c == 2) ? 0 : c + 1;
    cs = (cs == 2) ? 0 : cs + 1;
  }
#undef ASTG0
#undef ASTG1
}

// ================= fat-wave core, C++ LDS reads (control, as round 6) =================
__device__ __forceinline__ void gemm_fatC(
    const f16* __restrict__ A, const f16* __restrict__ Bt,
    int bm, int bn, f16* SM, int w, int lane, f32x4 (&acc)[8][4]) {
  constexpr int KT = 32;
  const int g = lane >> 4, rl = lane & 15;
  const int l4 = lane >> 2, ls = lane & 3;
  const int sslot = ls ^ ((l4 >> 1) & 3);

  const f16* aS = A + (size_t)(bm + w * 32 + l4) * 1024 + sslot * 8;
  const f16* bS = Bt + (size_t)(bn + w * 16 + l4) * 1024 + sslot * 8;
  f16* aD = SM + w * 1024;
  f16* bD = SM + 4096 + w * 512;

#define CSTG0(b, kt) do { \
    gl_lds16(aS + (kt) * 32,          aD + (b) * 12288); \
    gl_lds16(aS + 16384 + (kt) * 32,  aD + (b) * 12288 + 512); \
    gl_lds16(bS + (kt) * 32,          bD + (b) * 12288); } while (0)
#define CSTG1(b, kt) do { \
    gl_lds16(bS + 65536 + (kt) * 32,  bD + (b) * 12288 + 2048); \
    gl_lds16(bS + 131072 + (kt) * 32, bD + (b) * 12288 + 4096); \
    gl_lds16(bS + 196608 + (kt) * 32, bD + (b) * 12288 + 6144); } while (0)

  CSTG0(0, 0); CSTG1(0, 0);
  CSTG0(1, 1); CSTG1(1, 1);
  asm volatile("s_waitcnt vmcnt(6)" ::: "memory");
  __builtin_amdgcn_s_barrier();

  const int ro = rl * 32 + ((g ^ ((rl >> 1) & 3)) * 8);

  int c = 0, cs = 2;
#pragma unroll 1
  for (int kt = 0; kt < KT; ++kt) {
    const f16* SMc = SM + c * 12288;
    const bool stg = (kt + 2 < KT);
    f16x8 bf[4], af[4];
    {
#pragma unroll
      for (int j = 0; j < 4; ++j)
        bf[j] = *(const f16x8*)(SMc + 4096 + w * 2048 + j * 512 + ro);
#pragma unroll
      for (int mi = 0; mi < 4; ++mi)
        af[mi] = *(const f16x8*)(SMc + mi * 512 + ro);
      if (stg) CSTG0(cs, kt + 2);
      __builtin_amdgcn_s_barrier();
      asm volatile("s_waitcnt lgkmcnt(0)" ::: "memory");
      __builtin_amdgcn_sched_barrier(0);
      __builtin_amdgcn_s_setprio(1);
#pragma unroll
      for (int mi = 0; mi < 4; ++mi)
#pragma unroll
        for (int j = 0; j < 4; ++j)
          acc[mi][j] = mfma16(af[mi], bf[j], acc[mi][j]);
      __builtin_amdgcn_s_setprio(0);
      __builtin_amdgcn_sched_barrier(0);
      __builtin_amdgcn_s_barrier();
    }
    {
#pragma unroll
      for (int mi = 0; mi < 4; ++mi)
        af[mi] = *(const f16x8*)(SMc + (4 + mi) * 512 + ro);
      if (stg) CSTG1(cs, kt + 2);
      __builtin_amdgcn_s_barrier();
      asm volatile("s_waitcnt lgkmcnt(0)" ::: "memory");
      __builtin_amdgcn_sched_barrier(0);
      __builtin_amdgcn_s_setprio(1);
#pragma unroll
      for (int mi = 0; mi < 4; ++mi)
#pragma unroll
        for (int j = 0; j < 4; ++j)
          acc[4 + mi][j] = mfma16(af[mi], bf[j], acc[4 + mi][j]);
      __builtin_amdgcn_s_setprio(0);
      __builtin_amdgcn_sched_barrier(0);
      if (kt + 2 < KT)      { asm volatile("s_waitcnt vmcnt(6)" ::: "memory"); }
      else if (kt + 1 < KT) { asm volatile("s_waitcnt vmcnt(0)" ::: "memory"); }
      __builtin_amdgcn_s_barrier();
      __builtin_amdgcn_sched_barrier(0);
    }
    c = (c == 2) ? 0 : c + 1;
    cs = (cs == 2) ? 0 : cs + 1;
  }
#undef CSTG0
#undef CSTG1
}

// ---------------- QKV projection GEMM (asm-read experiment) ----------------
__global__ __launch_bounds__(256, 2) void k_gemm_qkv4(
    const f16* __restrict__ A, const f16* __restrict__ Bt,
    const float* __restrict__ bias,
    f16* __restrict__ qo, f16* __restrict__ ko2, f16* __restrict__ vto) {
  __shared__ __align__(16) f16 SM[36864];
  const int lin0 = blockIdx.y * 12 + blockIdx.x;
  const int lin = (lin0 & 7) * 96 + (lin0 >> 3);
  const int bn = (lin % 12) * 256, bm = (lin / 12) * 128;
  const int t = threadIdx.x, lane = t & 63, w = t >> 6;
  const int g = lane >> 4, rl = lane & 15;

  f32x4 acc[8][4] = {};
  gemm_fatA(A, Bt, bm, bn, SM, w, lane, acc);

#pragma unroll
  for (int mi = 0; mi < 8; ++mi)
#pragma unroll
    for (int j = 0; j < 4; ++j)
#pragma unroll
      for (int r = 0; r < 4; ++r) {
        int m = bm + mi * 16 + g * 4 + r;
        int n = bn + w * 64 + j * 16 + rl;
        float v = acc[mi][j][r] + bias[n];
        int b = m >> 11, s = m & 2047;
        int h = n / 192, rem = n - h * 192;
        int tsel = rem >> 6, d = rem & 63;
        size_t bh = (size_t)(b * 16 + h);
        if (tsel == 0)      qo[(bh * 2048 + s) * 64 + d] = (f16)(v * (0.125f * LOG2E));
        else if (tsel == 1) ko2[(bh * 2048 + s) * 64 + d] = (f16)v;
        else                vto[(bh * 64 + d) * 2048 + s] = (f16)v;
      }
}

// ---------------- output projection GEMM (control core) ----------------
__global__ __launch_bounds__(256, 2) void k_gemm_out4(
    const f16* __restrict__ A, const f16* __restrict__ Bt,
    const float* __restrict__ bias, float* __restrict__ out) {
  __shared__ __align__(16) f16 SM[36864];
  const int lin0 = blockIdx.y * 4 + blockIdx.x;
  const int lin = (lin0 & 7) * 32 + (lin0 >> 3);
  const int bn = (lin % 4) * 256, bm = (lin / 4) * 128;
  const int t = threadIdx.x, lane = t & 63, w = t >> 6;
  const int g = lane >> 4, rl = lane & 15;

  f32x4 acc[8][4] = {};
  gemm_fatC(A, Bt, bm, bn, SM, w, lane, acc);

#pragma unroll
  for (int mi = 0; mi < 8; ++mi)
#pragma unroll
    for (int j = 0; j < 4; ++j)
#pragma unroll
      for (int r = 0; r < 4; ++r) {
        int m = bm + mi * 16 + g * 4 + r;
        int n = bn + w * 64 + j * 16 + rl;
        out[(size_t)m * 1024 + n] = acc[mi][j][r] + bias[n];
      }
}

// ---------------- flash attention v3: K/V direct from L2, zero barriers ----------------
// K/V working set is 4MB/XCD (L2-resident via bh clustering) -> LDS staging was
// pure overhead (m169). Each wave fully independent; grid fully co-resident.
// q,k: [BH][2048][64] f16 ; vt: [BH][64][2048] f16 ; o: [8192][1024] f16
__global__ __launch_bounds__(256, 4) void k_attn2(
    const f16* __restrict__ q, const f16* __restrict__ kgl,
    const f16* __restrict__ vt, f16* __restrict__ o) {
  constexpr int S = 2048;
  __shared__ __align__(16) f16 Ps[4][32 * 64];  // per-wave P, both 16-row subs

  const int blk = blockIdx.x;
  const int sidx = blk >> 3;
  const int bh = (blk & 7) * 8 + (sidx & 7);   // XCD i owns bh [8i, 8i+8)
  const int qb = 15 - (sidx >> 3);

  const int t = threadIdx.x, lane = t & 63, w = t >> 6;
  const int g = lane >> 4, rl = lane & 15;

  const f16* qp = q + ((size_t)bh * S + qb * 128) * 64;
  const f16* kb = kgl + (size_t)bh * S * 64;
  const f16* vb = vt + (size_t)bh * 64 * S;

  f16x8 qf[2][2];
#pragma unroll
  for (int sub = 0; sub < 2; ++sub)
#pragma unroll
    for (int ks = 0; ks < 2; ++ks)
      qf[sub][ks] = *(const f16x8*)(qp + (size_t)(w * 32 + sub * 16 + rl) * 64 + ks * 32 + g * 8);

  f32x4 oacc[2][4] = {};
  float lrow[2] = {0.f, 0.f};

  // per-lane row bases (K row = rl + j*16; V row = rl + dj*16)
  const f16* kRow = kb + (size_t)rl * 64 + g * 8;
  const f16* vRow = vb + (size_t)rl * 2048 + g * 8;

  const int qsub0 = qb * 128 + w * 32;
  const int nktw = ((qsub0 + 31) >> 6) + 1;  // wave-local tile count (covers sub1 diag)

  for (int kt = 0; kt < nktw; ++kt) {
    // S^T = K Q^T for both subs, K loaded once from L2
    f32x4 sT[2][4] = {};
#pragma unroll
    for (int j = 0; j < 4; ++j)
#pragma unroll
      for (int ks = 0; ks < 2; ++ks) {
        f16x8 kf = *(const f16x8*)(kRow + (size_t)(kt * 64 + j * 16) * 64 + ks * 32);
        sT[0][j] = mfma16(kf, qf[0][ks], sT[0][j]);
        sT[1][j] = mfma16(kf, qf[1][ks], sT[1][j]);
      }

    // causal mask (handles fully-masked sub0 on sub1's diagonal tile too)
    if (kt * 64 + 63 > qsub0) {
#pragma unroll
      for (int sub = 0; sub < 2; ++sub) {
        const int qs = qsub0 + sub * 16;
#pragma unroll
        for (int j = 0; j < 4; ++j)
#pragma unroll
          for (int r = 0; r < 4; ++r)
            if (kt * 64 + j * 16 + g * 4 + r > qs + rl) sT[sub][j][r] = -1e30f;
      }
    }

    // shift-free softmax: p = 2^sT; write both subs' P to wave-private LDS
#pragma unroll
    for (int sub = 0; sub < 2; ++sub) {
      float ps = 0.f;
#pragma unroll
      for (int j = 0; j < 4; ++j) {
        f16x4 pb;
#pragma unroll
        for (int r = 0; r < 4; ++r) {
          float p = exp2f(sT[sub][j][r]);
          ps += p;
          pb[r] = (f16)p;
        }
        *(f16x4*)(&Ps[w][0] + (sub * 16 + rl) * 64 +
                  (((j * 2 + (g >> 1)) ^ (rl & 7)) * 8) + (g & 1) * 4) = pb;
      }
      lrow[sub] += ps;
    }

    asm volatile("s_waitcnt lgkmcnt(0)" ::: "memory");
    __builtin_amdgcn_sched_barrier(0);

    f16x8 pf[2][2];
#pragma unroll
    for (int sub = 0; sub < 2; ++sub)
#pragma unroll
      for (int ks = 0; ks < 2; ++ks)
        pf[sub][ks] = *(const f16x8*)(&Ps[w][0] + (sub * 16 + rl) * 64 +
                                      (((ks * 4 + g) ^ (rl & 7)) * 8));

    // O += P V, V loaded once from L2 for both subs
#pragma unroll
    for (int dj = 0; dj < 4; ++dj)
#pragma unroll
      for (int ks = 0; ks < 2; ++ks) {
        f16x8 vf = *(const f16x8*)(vRow + (size_t)(dj * 16) * 2048 + kt * 64 + ks * 32);
        oacc[0][dj] = mfma16(pf[0][ks], vf, oacc[0][dj]);
        oacc[1][dj] = mfma16(pf[1][ks], vf, oacc[1][dj]);
      }
  }

  float rinv[2];
#pragma unroll
  for (int sub = 0; sub < 2; ++sub) {
    float s_ = lrow[sub];
    s_ += __shfl_xor(s_, 16, 64);
    s_ += __shfl_xor(s_, 32, 64);
    rinv[sub] = 1.0f / s_;
  }

  const int h = bh & 15;
  const size_t rowb = (size_t)(bh >> 4) * 2048 + qb * 128 + w * 32;
#pragma unroll
  for (int sub = 0; sub < 2; ++sub)
#pragma unroll
    for (int r = 0; r < 4; ++r) {
      float ri = __shfl(rinv[sub], g * 4 + r, 64);
#pragma unroll
      for (int dj = 0; dj < 4; ++dj)
        o[(rowb + sub * 16 + g * 4 + r) * 1024 + h * 64 + dj * 16 + rl] =
            (f16)(oacc[sub][dj][r] * ri);
    }
}

extern "C" void kernel_launch(void* const* d_in, const int* in_sizes, int n_in,
                              void* d_out, int out_size, void* d_ws, size_t ws_size,
                              hipStream_t stream) {
  (void)in_sizes; (void)n_in; (void)out_size; (void)ws_size;
  const float* x    = (const float*)d_in[0];
  const float* wqkv = (const float*)d_in[1];
  const float* bqkv = (const float*)d_in[2];
  const float* wo   = (const float*)d_in[3];
  const float* bo   = (const float*)d_in[4];
  float* out = (float*)d_out;
  char* ws = (char*)d_ws;

  f16* xb    = (f16*)(ws + 0);          // x as f16 [8192][1024]
  f16* wqkvt = (f16*)(ws + 16777216);   // qkv_w^T f16 [3072][1024]
  f16* wot   = (f16*)(ws + 23068672);   // out_w^T f16 [1024][1024]
  f16* qws   = (f16*)(ws + 25165824);   // Q (pre-scaled 0.125*log2e)
  f16* kws   = (f16*)(ws + 41943040);   // K
  f16* vtws  = (f16*)(ws + 58720256);   // V^T
  f16* attnb = xb;

  k_cvt<<<2048, 256, 0, stream>>>(x, xb, 8388608 / 4);
  k_tconv<<<dim3(96, 32), dim3(32, 8), 0, stream>>>(wqkv, wqkvt, 1024, 3072);
  k_tconv<<<dim3(32, 32), dim3(32, 8), 0, stream>>>(wo, wot, 1024, 1024);
  k_gemm_qkv4<<<dim3(12, 64), 256, 0, stream>>>(xb, wqkvt, bqkv, qws, kws, vtws);
  k_attn2<<<1024, 256, 0, stream>>>(qws, kws, vtws, attnb);
  k_gemm_out4<<<dim3(4, 64), 256, 0, stream>>>(attnb, wot, bo, out);
}

// Round 8
// 199.322 us; speedup vs baseline: 1.3680x; 1.3680x over previous
//
#include <hip/hip_runtime.h>

typedef unsigned int u32;
typedef _Float16 f16;
typedef _Float16 f16x8 __attribute__((ext_vector_type(8)));
typedef _Float16 f16x4 __attribute__((ext_vector_type(4)));
typedef float f32x4 __attribute__((ext_vector_type(4)));
typedef _Float16 __attribute__((address_space(3))) lf16;

#define LOG2E 1.4426950408889634f

__device__ __forceinline__ void gl_lds16(const void* g, void* l) {
  __builtin_amdgcn_global_load_lds(
      (const __attribute__((address_space(1))) u32*)g,
      (__attribute__((address_space(3))) u32*)l, 16, 0, 0);
}

__device__ __forceinline__ f32x4 mfma16(f16x8 a, f16x8 b, f32x4 c) {
  return __builtin_amdgcn_mfma_f32_16x16x32_f16(a, b, c, 0, 0, 0);
}

// inline-asm LDS read (experiment core): compiler cannot see the op -> cannot
// insert conservative waits; we fence with lgkmcnt(0)+sched_barrier (rule #18).
__device__ __forceinline__ f16x8 ldsr(const f16* p) {
  f16x8 r;
  asm volatile("ds_read_b128 %0, %1" : "=v"(r) : "v"((const lf16*)p));
  return r;
}

// ---------------- fp32 -> fp16 convert ----------------
__global__ void k_cvt(const float* __restrict__ in, f16* __restrict__ out, int n4) {
  int stride = gridDim.x * blockDim.x;
  for (int i = blockIdx.x * blockDim.x + threadIdx.x; i < n4; i += stride) {
    f32x4 v = *(const f32x4*)(in + (size_t)i * 4);
    f16x4 o;
    o[0] = (f16)v[0]; o[1] = (f16)v[1]; o[2] = (f16)v[2]; o[3] = (f16)v[3];
    *(f16x4*)(out + (size_t)i * 4) = o;
  }
}

// ------------- transpose + convert -------------
__global__ void k_tconv(const float* __restrict__ in, f16* __restrict__ out, int R, int C) {
  __shared__ f16 tile[32][33];
  int c0 = blockIdx.x * 32, r0 = blockIdx.y * 32;
  int tx = threadIdx.x, ty = threadIdx.y;
#pragma unroll
  for (int i = ty; i < 32; i += 8)
    tile[i][tx] = (f16)in[(size_t)(r0 + i) * C + c0 + tx];
  __syncthreads();
#pragma unroll
  for (int i = ty; i < 32; i += 8)
    out[(size_t)(c0 + i) * R + r0 + tx] = tile[tx][i];
}

// ================= fat-wave core, ASM LDS reads (experiment) =================
__device__ __forceinline__ void gemm_fatA(
    const f16* __restrict__ A, const f16* __restrict__ Bt,
    int bm, int bn, f16* SM, int w, int lane, f32x4 (&acc)[8][4]) {
  constexpr int KT = 32;
  const int g = lane >> 4, rl = lane & 15;
  const int l4 = lane >> 2, ls = lane & 3;
  const int sslot = ls ^ ((l4 >> 1) & 3);

  const f16* aS = A + (size_t)(bm + w * 32 + l4) * 1024 + sslot * 8;
  const f16* bS = Bt + (size_t)(bn + w * 16 + l4) * 1024 + sslot * 8;
  f16* aD = SM + w * 1024;
  f16* bD = SM + 4096 + w * 512;

#define ASTG0(b, kt) do { \
    gl_lds16(aS + (kt) * 32,          aD + (b) * 12288); \
    gl_lds16(aS + 16384 + (kt) * 32,  aD + (b) * 12288 + 512); \
    gl_lds16(bS + (kt) * 32,          bD + (b) * 12288); } while (0)
#define ASTG1(b, kt) do { \
    gl_lds16(bS + 65536 + (kt) * 32,  bD + (b) * 12288 + 2048); \
    gl_lds16(bS + 131072 + (kt) * 32, bD + (b) * 12288 + 4096); \
    gl_lds16(bS + 196608 + (kt) * 32, bD + (b) * 12288 + 6144); } while (0)

  ASTG0(0, 0); ASTG1(0, 0);
  ASTG0(1, 1); ASTG1(1, 1);
  asm volatile("s_waitcnt vmcnt(6)" ::: "memory");
  __builtin_amdgcn_s_barrier();

  const int ro = rl * 32 + ((g ^ ((rl >> 1) & 3)) * 8);

  int c = 0, cs = 2;
#pragma unroll 1
  for (int kt = 0; kt < KT; ++kt) {
    const f16* SMc = SM + c * 12288;
    const bool stg = (kt + 2 < KT);
    f16x8 bf[4], af[4];

    {
#pragma unroll
      for (int j = 0; j < 4; ++j)
        bf[j] = ldsr(SMc + 4096 + w * 2048 + j * 512 + ro);
#pragma unroll
      for (int mi = 0; mi < 4; ++mi)
        af[mi] = ldsr(SMc + mi * 512 + ro);
      if (stg) ASTG0(cs, kt + 2);
      __builtin_amdgcn_s_barrier();
      asm volatile("s_waitcnt lgkmcnt(0)");
      __builtin_amdgcn_sched_barrier(0);
      __builtin_amdgcn_s_setprio(1);
#pragma unroll
      for (int mi = 0; mi < 4; ++mi)
#pragma unroll
        for (int j = 0; j < 4; ++j)
          acc[mi][j] = mfma16(af[mi], bf[j], acc[mi][j]);
      __builtin_amdgcn_s_setprio(0);
      __builtin_amdgcn_sched_barrier(0);
      __builtin_amdgcn_s_barrier();
    }
    {
#pragma unroll
      for (int mi = 0; mi < 4; ++mi)
        af[mi] = ldsr(SMc + (4 + mi) * 512 + ro);
      if (stg) ASTG1(cs, kt + 2);
      __builtin_amdgcn_s_barrier();
      asm volatile("s_waitcnt lgkmcnt(0)");
      __builtin_amdgcn_sched_barrier(0);
      __builtin_amdgcn_s_setprio(1);
#pragma unroll
      for (int mi = 0; mi < 4; ++mi)
#pragma unroll
        for (int j = 0; j < 4; ++j)
          acc[4 + mi][j] = mfma16(af[mi], bf[j], acc[4 + mi][j]);
      __builtin_amdgcn_s_setprio(0);
      __builtin_amdgcn_sched_barrier(0);
      if (kt + 2 < KT)      { asm volatile("s_waitcnt vmcnt(6)" ::: "memory"); }
      else if (kt + 1 < KT) { asm volatile("s_waitcnt vmcnt(0)" ::: "memory"); }
      __builtin_amdgcn_s_barrier();
      __builtin_amdgcn_sched_barrier(0);
    }
    c = (c == 2) ? 0 : c + 1;
    cs = (cs == 2) ? 0 : cs + 1;
  }
#undef ASTG0
#undef ASTG1
}

// ================= fat-wave core, C++ LDS reads (control) =================
__device__ __forceinline__ void gemm_fatC(
    const f16* __restrict__ A, const f16* __restrict__ Bt,
    int bm, int bn, f16* SM, int w, int lane, f32x4 (&acc)[8][4]) {
  constexpr int KT = 32;
  const int g = lane >> 4, rl = lane & 15;
  const int l4 = lane >> 2, ls = lane & 3;
  const int sslot = ls ^ ((l4 >> 1) & 3);

  const f16* aS = A + (size_t)(bm + w * 32 + l4) * 1024 + sslot * 8;
  const f16* bS = Bt + (size_t)(bn + w * 16 + l4) * 1024 + sslot * 8;
  f16* aD = SM + w * 1024;
  f16* bD = SM + 4096 + w * 512;

#define CSTG0(b, kt) do { \
    gl_lds16(aS + (kt) * 32,          aD + (b) * 12288); \
    gl_lds16(aS + 16384 + (kt) * 32,  aD + (b) * 12288 + 512); \
    gl_lds16(bS + (kt) * 32,          bD + (b) * 12288); } while (0)
#define CSTG1(b, kt) do { \
    gl_lds16(bS + 65536 + (kt) * 32,  bD + (b) * 12288 + 2048); \
    gl_lds16(bS + 131072 + (kt) * 32, bD + (b) * 12288 + 4096); \
    gl_lds16(bS + 196608 + (kt) * 32, bD + (b) * 12288 + 6144); } while (0)

  CSTG0(0, 0); CSTG1(0, 0);
  CSTG0(1, 1); CSTG1(1, 1);
  asm volatile("s_waitcnt vmcnt(6)" ::: "memory");
  __builtin_amdgcn_s_barrier();

  const int ro = rl * 32 + ((g ^ ((rl >> 1) & 3)) * 8);

  int c = 0, cs = 2;
#pragma unroll 1
  for (int kt = 0; kt < KT; ++kt) {
    const f16* SMc = SM + c * 12288;
    const bool stg = (kt + 2 < KT);
    f16x8 bf[4], af[4];
    {
#pragma unroll
      for (int j = 0; j < 4; ++j)
        bf[j] = *(const f16x8*)(SMc + 4096 + w * 2048 + j * 512 + ro);
#pragma unroll
      for (int mi = 0; mi < 4; ++mi)
        af[mi] = *(const f16x8*)(SMc + mi * 512 + ro);
      if (stg) CSTG0(cs, kt + 2);
      __builtin_amdgcn_s_barrier();
      asm volatile("s_waitcnt lgkmcnt(0)" ::: "memory");
      __builtin_amdgcn_sched_barrier(0);
      __builtin_amdgcn_s_setprio(1);
#pragma unroll
      for (int mi = 0; mi < 4; ++mi)
#pragma unroll
        for (int j = 0; j < 4; ++j)
          acc[mi][j] = mfma16(af[mi], bf[j], acc[mi][j]);
      __builtin_amdgcn_s_setprio(0);
      __builtin_amdgcn_sched_barrier(0);
      __builtin_amdgcn_s_barrier();
    }
    {
#pragma unroll
      for (int mi = 0; mi < 4; ++mi)
        af[mi] = *(const f16x8*)(SMc + (4 + mi) * 512 + ro);
      if (stg) CSTG1(cs, kt + 2);
      __builtin_amdgcn_s_barrier();
      asm volatile("s_waitcnt lgkmcnt(0)" ::: "memory");
      __builtin_amdgcn_sched_barrier(0);
      __builtin_amdgcn_s_setprio(1);
#pragma unroll
      for (int mi = 0; mi < 4; ++mi)
#pragma unroll
        for (int j = 0; j < 4; ++j)
          acc[4 + mi][j] = mfma16(af[mi], bf[j], acc[4 + mi][j]);
      __builtin_amdgcn_s_setprio(0);
      __builtin_amdgcn_sched_barrier(0);
      if (kt + 2 < KT)      { asm volatile("s_waitcnt vmcnt(6)" ::: "memory"); }
      else if (kt + 1 < KT) { asm volatile("s_waitcnt vmcnt(0)" ::: "memory"); }
      __builtin_amdgcn_s_barrier();
      __builtin_amdgcn_sched_barrier(0);
    }
    c = (c == 2) ? 0 : c + 1;
    cs = (cs == 2) ? 0 : cs + 1;
  }
#undef CSTG0
#undef CSTG1
}

// ---------------- QKV projection GEMM (asm-read experiment) ----------------
__global__ __launch_bounds__(256, 2) void k_gemm_qkv4(
    const f16* __restrict__ A, const f16* __restrict__ Bt,
    const float* __restrict__ bias,
    f16* __restrict__ qo, f16* __restrict__ ko2, f16* __restrict__ vto) {
  __shared__ __align__(16) f16 SM[36864];
  const int lin0 = blockIdx.y * 12 + blockIdx.x;
  const int lin = (lin0 & 7) * 96 + (lin0 >> 3);
  const int bn = (lin % 12) * 256, bm = (lin / 12) * 128;
  const int t = threadIdx.x, lane = t & 63, w = t >> 6;
  const int g = lane >> 4, rl = lane & 15;

  f32x4 acc[8][4] = {};
  gemm_fatA(A, Bt, bm, bn, SM, w, lane, acc);

#pragma unroll
  for (int mi = 0; mi < 8; ++mi)
#pragma unroll
    for (int j = 0; j < 4; ++j)
#pragma unroll
      for (int r = 0; r < 4; ++r) {
        int m = bm + mi * 16 + g * 4 + r;
        int n = bn + w * 64 + j * 16 + rl;
        float v = acc[mi][j][r] + bias[n];
        int b = m >> 11, s = m & 2047;
        int h = n / 192, rem = n - h * 192;
        int tsel = rem >> 6, d = rem & 63;
        size_t bh = (size_t)(b * 16 + h);
        if (tsel == 0)      qo[(bh * 2048 + s) * 64 + d] = (f16)(v * (0.125f * LOG2E));
        else if (tsel == 1) ko2[(bh * 2048 + s) * 64 + d] = (f16)v;
        else                vto[(bh * 64 + d) * 2048 + s] = (f16)v;
      }
}

// ---------------- output projection GEMM (control core) ----------------
__global__ __launch_bounds__(256, 2) void k_gemm_out4(
    const f16* __restrict__ A, const f16* __restrict__ Bt,
    const float* __restrict__ bias, float* __restrict__ out) {
  __shared__ __align__(16) f16 SM[36864];
  const int lin0 = blockIdx.y * 4 + blockIdx.x;
  const int lin = (lin0 & 7) * 32 + (lin0 >> 3);
  const int bn = (lin % 4) * 256, bm = (lin / 4) * 128;
  const int t = threadIdx.x, lane = t & 63, w = t >> 6;
  const int g = lane >> 4, rl = lane & 15;

  f32x4 acc[8][4] = {};
  gemm_fatC(A, Bt, bm, bn, SM, w, lane, acc);

#pragma unroll
  for (int mi = 0; mi < 8; ++mi)
#pragma unroll
    for (int j = 0; j < 4; ++j)
#pragma unroll
      for (int r = 0; r < 4; ++r) {
        int m = bm + mi * 16 + g * 4 + r;
        int n = bn + w * 64 + j * 16 + rl;
        out[(size_t)m * 1024 + n] = acc[mi][j][r] + bias[n];
      }
}

// ---------------- flash attention v4: LDS-staged (round-6 body), paired-qb balance ----------------
// 512 blocks, each does qb=15-p then qb=p -> EVERY block = exactly 34 k-tiles,
// balance independent of block->CU placement. 2 blocks/CU all-resident (LDS 80KB).
__global__ __launch_bounds__(256, 2) void k_attn4(
    const f16* __restrict__ q, const f16* __restrict__ kgl,
    const f16* __restrict__ vt, f16* __restrict__ o) {
  constexpr int S = 2048;
  __shared__ __align__(16) f16 Ks[2][64 * 64];
  __shared__ __align__(16) f16 Vs[2][64 * 64];
  __shared__ __align__(16) f16 Ps[4][16 * 64];

  const int blk = blockIdx.x;
  const int bh = (blk & 7) * 8 + ((blk >> 3) & 7);  // XCD i owns bh [8i,8i+8)
  const int p = blk >> 6;                            // 0..7 pair index

  const int t = threadIdx.x, lane = t & 63, w = t >> 6;
  const int g = lane >> 4, rl = lane & 15;

  const f16* kb = kgl + (size_t)bh * S * 64;
  const f16* vb = vt + (size_t)bh * 64 * S;
  const int srow = lane >> 3;
  const int sslot = (lane & 7) ^ srow;
  const int h = bh & 15;

  auto STAGE = [&](int bufi, int kt) {
#pragma unroll
    for (int i = 0; i < 2; ++i) {
      const int r0 = w * 16 + i * 8;
      gl_lds16(kb + (size_t)(kt * 64 + r0 + srow) * 64 + sslot * 8, &Ks[bufi][r0 * 64]);
      gl_lds16(vb + (size_t)(r0 + srow) * S + kt * 64 + sslot * 8, &Vs[bufi][r0 * 64]);
    }
  };

#pragma unroll 1
  for (int half = 0; half < 2; ++half) {
    const int qb = half ? p : 15 - p;
    const f16* qp = q + ((size_t)bh * S + qb * 128) * 64;

    f16x8 qf[2][2];
#pragma unroll
    for (int sub = 0; sub < 2; ++sub)
#pragma unroll
      for (int ks = 0; ks < 2; ++ks)
        qf[sub][ks] = *(const f16x8*)(qp + (size_t)(w * 32 + sub * 16 + rl) * 64 + ks * 32 + g * 8);

    f32x4 oacc[2][4] = {};
    float lrow[2] = {0.f, 0.f};

    const int nkt = 2 * qb + 2;
    const int qmaxw = qb * 128 + w * 32 + 31;

    STAGE(0, 0);
    __syncthreads();
    int buf = 0;

    for (int kt = 0; kt < nkt; ++kt) {
      if (kt + 1 < nkt) STAGE(buf ^ 1, kt + 1);

      if (kt * 64 <= qmaxw) {
        const f16* Kb = &Ks[buf][0];
        const f16* Vb = &Vs[buf][0];
#pragma unroll
        for (int sub = 0; sub < 2; ++sub) {
          const int qsub = qb * 128 + w * 32 + sub * 16;
          if (kt * 64 > qsub + 15) continue;

          f32x4 sT[4] = {};
#pragma unroll
          for (int j = 0; j < 4; ++j)
#pragma unroll
            for (int ks = 0; ks < 2; ++ks) {
              int row = j * 16 + rl;
              f16x8 kf = *(const f16x8*)(Kb + row * 64 + (((ks * 4 + g) ^ (rl & 7)) * 8));
              sT[j] = mfma16(kf, qf[sub][ks], sT[j]);
            }

          if (kt * 64 + 63 > qsub) {
#pragma unroll
            for (int j = 0; j < 4; ++j)
#pragma unroll
              for (int r = 0; r < 4; ++r)
                if (kt * 64 + j * 16 + g * 4 + r > qsub + rl) sT[j][r] = -1e30f;
          }

          float ps = 0.f;
#pragma unroll
          for (int j = 0; j < 4; ++j) {
            f16x4 pb;
#pragma unroll
            for (int r = 0; r < 4; ++r) {
              float pp = exp2f(sT[j][r]);
              ps += pp;
              pb[r] = (f16)pp;
            }
            *(f16x4*)(&Ps[w][0] + rl * 64 + (((j * 2 + (g >> 1)) ^ (rl & 7)) * 8) + (g & 1) * 4) = pb;
          }
          lrow[sub] += ps;

          asm volatile("s_waitcnt lgkmcnt(0)" ::: "memory");
          __builtin_amdgcn_sched_barrier(0);

          f16x8 pf[2];
#pragma unroll
          for (int ks = 0; ks < 2; ++ks)
            pf[ks] = *(const f16x8*)(&Ps[w][0] + rl * 64 + (((ks * 4 + g) ^ (rl & 7)) * 8));

#pragma unroll
          for (int dj = 0; dj < 4; ++dj)
#pragma unroll
            for (int ks = 0; ks < 2; ++ks) {
              int vrow = dj * 16 + rl;
              f16x8 vf = *(const f16x8*)(Vb + vrow * 64 + (((ks * 4 + g) ^ (rl & 7)) * 8));
              oacc[sub][dj] = mfma16(pf[ks], vf, oacc[sub][dj]);
            }
        }
      }
      __syncthreads();
      buf ^= 1;
    }

    float rinv[2];
#pragma unroll
    for (int sub = 0; sub < 2; ++sub) {
      float s_ = lrow[sub];
      s_ += __shfl_xor(s_, 16, 64);
      s_ += __shfl_xor(s_, 32, 64);
      rinv[sub] = 1.0f / s_;
    }

    const size_t rowb = (size_t)(bh >> 4) * 2048 + qb * 128 + w * 32;
#pragma unroll
    for (int sub = 0; sub < 2; ++sub)
#pragma unroll
      for (int r = 0; r < 4; ++r) {
        float ri = __shfl(rinv[sub], g * 4 + r, 64);
#pragma unroll
        for (int dj = 0; dj < 4; ++dj)
          o[(rowb + sub * 16 + g * 4 + r) * 1024 + h * 64 + dj * 16 + rl] =
              (f16)(oacc[sub][dj][r] * ri);
      }
  }
}

extern "C" void kernel_launch(void* const* d_in, const int* in_sizes, int n_in,
                              void* d_out, int out_size, void* d_ws, size_t ws_size,
                              hipStream_t stream) {
  (void)in_sizes; (void)n_in; (void)out_size; (void)ws_size;
  const float* x    = (const float*)d_in[0];
  const float* wqkv = (const float*)d_in[1];
  const float* bqkv = (const float*)d_in[2];
  const float* wo   = (const float*)d_in[3];
  const float* bo   = (const float*)d_in[4];
  float* out = (float*)d_out;
  char* ws = (char*)d_ws;

  f16* xb    = (f16*)(ws + 0);          // x as f16 [8192][1024]
  f16* wqkvt = (f16*)(ws + 16777216);   // qkv_w^T f16 [3072][1024]
  f16* wot   = (f16*)(ws + 23068672);   // out_w^T f16 [1024][1024]
  f16* qws   = (f16*)(ws + 25165824);   // Q (pre-scaled 0.125*log2e)
  f16* kws   = (f16*)(ws + 41943040);   // K
  f16* vtws  = (f16*)(ws + 58720256);   // V^T
  f16* attnb = xb;

  k_cvt<<<2048, 256, 0, stream>>>(x, xb, 8388608 / 4);
  k_tconv<<<dim3(96, 32), dim3(32, 8), 0, stream>>>(wqkv, wqkvt, 1024, 3072);
  k_tconv<<<dim3(32, 32), dim3(32, 8), 0, stream>>>(wo, wot, 1024, 1024);
  k_gemm_qkv4<<<dim3(12, 64), 256, 0, stream>>>(xb, wqkvt, bqkv, qws, kws, vtws);
  k_attn4<<<512, 256, 0, stream>>>(qws, kws, vtws, attnb);
  k_gemm_out4<<<dim3(4, 64), 256, 0, stream>>>(attnb, wot, bo, out);
}

// Round 9
// 187.884 us; speedup vs baseline: 1.4513x; 1.0609x over previous
//
#include <hip/hip_runtime.h>

typedef unsigned int u32;
typedef _Float16 f16;
typedef _Float16 f16x8 __attribute__((ext_vector_type(8)));
typedef _Float16 f16x4 __attribute__((ext_vector_type(4)));
typedef float f32x4 __attribute__((ext_vector_type(4)));
typedef _Float16 __attribute__((address_space(3))) lf16;

#define LOG2E 1.4426950408889634f

__device__ __forceinline__ void gl_lds16(const void* g, void* l) {
  __builtin_amdgcn_global_load_lds(
      (const __attribute__((address_space(1))) u32*)g,
      (__attribute__((address_space(3))) u32*)l, 16, 0, 0);
}

__device__ __forceinline__ f32x4 mfma16(f16x8 a, f16x8 b, f32x4 c) {
  return __builtin_amdgcn_mfma_f32_16x16x32_f16(a, b, c, 0, 0, 0);
}

// inline-asm LDS read (qkv experiment core): compiler cannot see the op ->
// cannot insert conservative waits; we fence per rule #18.
__device__ __forceinline__ f16x8 ldsr(const f16* p) {
  f16x8 r;
  asm volatile("ds_read_b128 %0, %1" : "=v"(r) : "v"((const lf16*)p));
  return r;
}

// ---------------- fp32 -> fp16 convert ----------------
__global__ void k_cvt(const float* __restrict__ in, f16* __restrict__ out, int n4) {
  int stride = gridDim.x * blockDim.x;
  for (int i = blockIdx.x * blockDim.x + threadIdx.x; i < n4; i += stride) {
    f32x4 v = *(const f32x4*)(in + (size_t)i * 4);
    f16x4 o;
    o[0] = (f16)v[0]; o[1] = (f16)v[1]; o[2] = (f16)v[2]; o[3] = (f16)v[3];
    *(f16x4*)(out + (size_t)i * 4) = o;
  }
}

// ------------- transpose + convert -------------
__global__ void k_tconv(const float* __restrict__ in, f16* __restrict__ out, int R, int C) {
  __shared__ f16 tile[32][33];
  int c0 = blockIdx.x * 32, r0 = blockIdx.y * 32;
  int tx = threadIdx.x, ty = threadIdx.y;
#pragma unroll
  for (int i = ty; i < 32; i += 8)
    tile[i][tx] = (f16)in[(size_t)(r0 + i) * C + c0 + tx];
  __syncthreads();
#pragma unroll
  for (int i = ty; i < 32; i += 8)
    out[(size_t)(c0 + i) * R + r0 + tx] = tile[tx][i];
}

// ================= fat-wave core, ASM LDS reads (qkv) =================
__device__ __forceinline__ void gemm_fatA(
    const f16* __restrict__ A, const f16* __restrict__ Bt,
    int bm, int bn, f16* SM, int w, int lane, f32x4 (&acc)[8][4]) {
  constexpr int KT = 32;
  const int g = lane >> 4, rl = lane & 15;
  const int l4 = lane >> 2, ls = lane & 3;
  const int sslot = ls ^ ((l4 >> 1) & 3);

  const f16* aS = A + (size_t)(bm + w * 32 + l4) * 1024 + sslot * 8;
  const f16* bS = Bt + (size_t)(bn + w * 16 + l4) * 1024 + sslot * 8;
  f16* aD = SM + w * 1024;
  f16* bD = SM + 4096 + w * 512;

#define ASTG0(b, kt) do { \
    gl_lds16(aS + (kt) * 32,          aD + (b) * 12288); \
    gl_lds16(aS + 16384 + (kt) * 32,  aD + (b) * 12288 + 512); \
    gl_lds16(bS + (kt) * 32,          bD + (b) * 12288); } while (0)
#define ASTG1(b, kt) do { \
    gl_lds16(bS + 65536 + (kt) * 32,  bD + (b) * 12288 + 2048); \
    gl_lds16(bS + 131072 + (kt) * 32, bD + (b) * 12288 + 4096); \
    gl_lds16(bS + 196608 + (kt) * 32, bD + (b) * 12288 + 6144); } while (0)

  ASTG0(0, 0); ASTG1(0, 0);
  ASTG0(1, 1); ASTG1(1, 1);
  asm volatile("s_waitcnt vmcnt(6)" ::: "memory");
  __builtin_amdgcn_s_barrier();

  const int ro = rl * 32 + ((g ^ ((rl >> 1) & 3)) * 8);

  int c = 0, cs = 2;
#pragma unroll 1
  for (int kt = 0; kt < KT; ++kt) {
    const f16* SMc = SM + c * 12288;
    const bool stg = (kt + 2 < KT);
    f16x8 bf[4], af[4];

    {
#pragma unroll
      for (int j = 0; j < 4; ++j)
        bf[j] = ldsr(SMc + 4096 + w * 2048 + j * 512 + ro);
#pragma unroll
      for (int mi = 0; mi < 4; ++mi)
        af[mi] = ldsr(SMc + mi * 512 + ro);
      if (stg) ASTG0(cs, kt + 2);
      __builtin_amdgcn_s_barrier();
      asm volatile("s_waitcnt lgkmcnt(0)");
      __builtin_amdgcn_sched_barrier(0);
      __builtin_amdgcn_s_setprio(1);
#pragma unroll
      for (int mi = 0; mi < 4; ++mi)
#pragma unroll
        for (int j = 0; j < 4; ++j)
          acc[mi][j] = mfma16(af[mi], bf[j], acc[mi][j]);
      __builtin_amdgcn_s_setprio(0);
      __builtin_amdgcn_sched_barrier(0);
      __builtin_amdgcn_s_barrier();
    }
    {
#pragma unroll
      for (int mi = 0; mi < 4; ++mi)
        af[mi] = ldsr(SMc + (4 + mi) * 512 + ro);
      if (stg) ASTG1(cs, kt + 2);
      __builtin_amdgcn_s_barrier();
      asm volatile("s_waitcnt lgkmcnt(0)");
      __builtin_amdgcn_sched_barrier(0);
      __builtin_amdgcn_s_setprio(1);
#pragma unroll
      for (int mi = 0; mi < 4; ++mi)
#pragma unroll
        for (int j = 0; j < 4; ++j)
          acc[4 + mi][j] = mfma16(af[mi], bf[j], acc[4 + mi][j]);
      __builtin_amdgcn_s_setprio(0);
      __builtin_amdgcn_sched_barrier(0);
      if (kt + 2 < KT)      { asm volatile("s_waitcnt vmcnt(6)" ::: "memory"); }
      else if (kt + 1 < KT) { asm volatile("s_waitcnt vmcnt(0)" ::: "memory"); }
      __builtin_amdgcn_s_barrier();
      __builtin_amdgcn_sched_barrier(0);
    }
    c = (c == 2) ? 0 : c + 1;
    cs = (cs == 2) ? 0 : cs + 1;
  }
#undef ASTG0
#undef ASTG1
}

// ================= fat-wave core, C++ LDS reads (out, control) =================
__device__ __forceinline__ void gemm_fatC(
    const f16* __restrict__ A, const f16* __restrict__ Bt,
    int bm, int bn, f16* SM, int w, int lane, f32x4 (&acc)[8][4]) {
  constexpr int KT = 32;
  const int g = lane >> 4, rl = lane & 15;
  const int l4 = lane >> 2, ls = lane & 3;
  const int sslot = ls ^ ((l4 >> 1) & 3);

  const f16* aS = A + (size_t)(bm + w * 32 + l4) * 1024 + sslot * 8;
  const f16* bS = Bt + (size_t)(bn + w * 16 + l4) * 1024 + sslot * 8;
  f16* aD = SM + w * 1024;
  f16* bD = SM + 4096 + w * 512;

#define CSTG0(b, kt) do { \
    gl_lds16(aS + (kt) * 32,          aD + (b) * 12288); \
    gl_lds16(aS + 16384 + (kt) * 32,  aD + (b) * 12288 + 512); \
    gl_lds16(bS + (kt) * 32,          bD + (b) * 12288); } while (0)
#define CSTG1(b, kt) do { \
    gl_lds16(bS + 65536 + (kt) * 32,  bD + (b) * 12288 + 2048); \
    gl_lds16(bS + 131072 + (kt) * 32, bD + (b) * 12288 + 4096); \
    gl_lds16(bS + 196608 + (kt) * 32, bD + (b) * 12288 + 6144); } while (0)

  CSTG0(0, 0); CSTG1(0, 0);
  CSTG0(1, 1); CSTG1(1, 1);
  asm volatile("s_waitcnt vmcnt(6)" ::: "memory");
  __builtin_amdgcn_s_barrier();

  const int ro = rl * 32 + ((g ^ ((rl >> 1) & 3)) * 8);

  int c = 0, cs = 2;
#pragma unroll 1
  for (int kt = 0; kt < KT; ++kt) {
    const f16* SMc = SM + c * 12288;
    const bool stg = (kt + 2 < KT);
    f16x8 bf[4], af[4];
    {
#pragma unroll
      for (int j = 0; j < 4; ++j)
        bf[j] = *(const f16x8*)(SMc + 4096 + w * 2048 + j * 512 + ro);
#pragma unroll
      for (int mi = 0; mi < 4; ++mi)
        af[mi] = *(const f16x8*)(SMc + mi * 512 + ro);
      if (stg) CSTG0(cs, kt + 2);
      __builtin_amdgcn_s_barrier();
      asm volatile("s_waitcnt lgkmcnt(0)" ::: "memory");
      __builtin_amdgcn_sched_barrier(0);
      __builtin_amdgcn_s_setprio(1);
#pragma unroll
      for (int mi = 0; mi < 4; ++mi)
#pragma unroll
        for (int j = 0; j < 4; ++j)
          acc[mi][j] = mfma16(af[mi], bf[j], acc[mi][j]);
      __builtin_amdgcn_s_setprio(0);
      __builtin_amdgcn_sched_barrier(0);
      __builtin_amdgcn_s_barrier();
    }
    {
#pragma unroll
      for (int mi = 0; mi < 4; ++mi)
        af[mi] = *(const f16x8*)(SMc + (4 + mi) * 512 + ro);
      if (stg) CSTG1(cs, kt + 2);
      __builtin_amdgcn_s_barrier();
      asm volatile("s_waitcnt lgkmcnt(0)" ::: "memory");
      __builtin_amdgcn_sched_barrier(0);
      __builtin_amdgcn_s_setprio(1);
#pragma unroll
      for (int mi = 0; mi < 4; ++mi)
#pragma unroll
        for (int j = 0; j < 4; ++j)
          acc[4 + mi][j] = mfma16(af[mi], bf[j], acc[4 + mi][j]);
      __builtin_amdgcn_s_setprio(0);
      __builtin_amdgcn_sched_barrier(0);
      if (kt + 2 < KT)      { asm volatile("s_waitcnt vmcnt(6)" ::: "memory"); }
      else if (kt + 1 < KT) { asm volatile("s_waitcnt vmcnt(0)" ::: "memory"); }
      __builtin_amdgcn_s_barrier();
      __builtin_amdgcn_sched_barrier(0);
    }
    c = (c == 2) ? 0 : c + 1;
    cs = (cs == 2) ? 0 : cs + 1;
  }
#undef CSTG0
#undef CSTG1
}

// ---------------- QKV projection GEMM ----------------
__global__ __launch_bounds__(256, 2) void k_gemm_qkv4(
    const f16* __restrict__ A, const f16* __restrict__ Bt,
    const float* __restrict__ bias,
    f16* __restrict__ qo, f16* __restrict__ ko2, f16* __restrict__ vto) {
  __shared__ __align__(16) f16 SM[36864];
  const int lin0 = blockIdx.y * 12 + blockIdx.x;
  const int lin = (lin0 & 7) * 96 + (lin0 >> 3);
  const int bn = (lin % 12) * 256, bm = (lin / 12) * 128;
  const int t = threadIdx.x, lane = t & 63, w = t >> 6;
  const int g = lane >> 4, rl = lane & 15;

  f32x4 acc[8][4] = {};
  gemm_fatA(A, Bt, bm, bn, SM, w, lane, acc);

#pragma unroll
  for (int mi = 0; mi < 8; ++mi)
#pragma unroll
    for (int j = 0; j < 4; ++j)
#pragma unroll
      for (int r = 0; r < 4; ++r) {
        int m = bm + mi * 16 + g * 4 + r;
        int n = bn + w * 64 + j * 16 + rl;
        float v = acc[mi][j][r] + bias[n];
        int b = m >> 11, s = m & 2047;
        int h = n / 192, rem = n - h * 192;
        int tsel = rem >> 6, dd = rem & 63;
        size_t bh = (size_t)(b * 16 + h);
        if (tsel == 0)      qo[(bh * 2048 + s) * 64 + dd] = (f16)(v * (0.125f * LOG2E));
        else if (tsel == 1) ko2[(bh * 2048 + s) * 64 + dd] = (f16)v;
        else                vto[(bh * 64 + dd) * 2048 + s] = (f16)v;
      }
}

// ---------------- output projection GEMM ----------------
__global__ __launch_bounds__(256, 2) void k_gemm_out4(
    const f16* __restrict__ A, const f16* __restrict__ Bt,
    const float* __restrict__ bias, float* __restrict__ out) {
  __shared__ __align__(16) f16 SM[36864];
  const int lin0 = blockIdx.y * 4 + blockIdx.x;
  const int lin = (lin0 & 7) * 32 + (lin0 >> 3);
  const int bn = (lin % 4) * 256, bm = (lin / 4) * 128;
  const int t = threadIdx.x, lane = t & 63, w = t >> 6;
  const int g = lane >> 4, rl = lane & 15;

  f32x4 acc[8][4] = {};
  gemm_fatC(A, Bt, bm, bn, SM, w, lane, acc);

#pragma unroll
  for (int mi = 0; mi < 8; ++mi)
#pragma unroll
    for (int j = 0; j < 4; ++j)
#pragma unroll
      for (int r = 0; r < 4; ++r) {
        int m = bm + mi * 16 + g * 4 + r;
        int n = bn + w * 64 + j * 16 + rl;
        out[(size_t)m * 1024 + n] = acc[mi][j][r] + bias[n];
      }
}

// ---------------- flash attention v5 ----------------
// Round-6 attn2 body (1024 blocks, 4 blocks/CU, LDS-staged dbuf K/V) +
// merged QK^T (K-frag loaded once feeds both q-subs: -8 ds_read/tile) +
// balanced qb permutation (per-CU work sums to 68 tiles under round-robin).
__global__ __launch_bounds__(256, 4) void k_attn5(
    const f16* __restrict__ q, const f16* __restrict__ kgl,
    const f16* __restrict__ vt, f16* __restrict__ o) {
  constexpr int S = 2048;
  __shared__ __align__(16) f16 Ks[2][64 * 64];
  __shared__ __align__(16) f16 Vs[2][64 * 64];
  __shared__ __align__(16) f16 Ps[4][16 * 64];

  const int d = blockIdx.x;
  const int bh = (d & 7) * 8 + ((d >> 3) & 7);  // XCD i owns bh [8i,8i+8)
  // balanced qb: CU r's 4 blocks (r, r+256, r+512, r+768) get qb summing to 30
  const int v_ = d >> 6, g2 = v_ >> 2, r2 = v_ & 3;
  const int qb = (g2 == 0) ? 15 - r2 : (g2 == 1) ? r2 : (g2 == 2) ? 11 - r2 : 4 + r2;

  const int t = threadIdx.x, lane = t & 63, w = t >> 6;
  const int g = lane >> 4, rl = lane & 15;

  const f16* qp = q + ((size_t)bh * S + qb * 128) * 64;
  const f16* kb = kgl + (size_t)bh * S * 64;
  const f16* vb = vt + (size_t)bh * 64 * S;

  f16x8 qf[2][2];
#pragma unroll
  for (int sub = 0; sub < 2; ++sub)
#pragma unroll
    for (int ks = 0; ks < 2; ++ks)
      qf[sub][ks] = *(const f16x8*)(qp + (size_t)(w * 32 + sub * 16 + rl) * 64 + ks * 32 + g * 8);

  f32x4 oacc[2][4] = {};
  float lrow[2] = {0.f, 0.f};

  const int srow = lane >> 3;
  const int sslot = (lane & 7) ^ srow;

  const int nkt = 2 * qb + 2;
  const int qsub0 = qb * 128 + w * 32;
  const int qmaxw = qsub0 + 31;

  auto STAGE = [&](int bufi, int kt) {
#pragma unroll
    for (int i = 0; i < 2; ++i) {
      const int r0 = w * 16 + i * 8;
      gl_lds16(kb + (size_t)(kt * 64 + r0 + srow) * 64 + sslot * 8, &Ks[bufi][r0 * 64]);
      gl_lds16(vb + (size_t)(r0 + srow) * S + kt * 64 + sslot * 8, &Vs[bufi][r0 * 64]);
    }
  };

  STAGE(0, 0);
  __syncthreads();
  int buf = 0;

  for (int kt = 0; kt < nkt; ++kt) {
    if (kt + 1 < nkt) STAGE(buf ^ 1, kt + 1);

    if (kt * 64 <= qmaxw) {
      const f16* Kb = &Ks[buf][0];
      const f16* Vb = &Vs[buf][0];

      // merged QK^T: each K-fragment feeds both subs
      f32x4 sT[2][4] = {};
#pragma unroll
      for (int j = 0; j < 4; ++j)
#pragma unroll
        for (int ks = 0; ks < 2; ++ks) {
          int row = j * 16 + rl;
          f16x8 kf = *(const f16x8*)(Kb + row * 64 + (((ks * 4 + g) ^ (rl & 7)) * 8));
          sT[0][j] = mfma16(kf, qf[0][ks], sT[0][j]);
          sT[1][j] = mfma16(kf, qf[1][ks], sT[1][j]);
        }

      if (kt * 64 + 63 > qsub0) {  // boundary: causal mask both subs
#pragma unroll
        for (int sub = 0; sub < 2; ++sub) {
          const int qs = qsub0 + sub * 16;
#pragma unroll
          for (int j = 0; j < 4; ++j)
#pragma unroll
            for (int r = 0; r < 4; ++r)
              if (kt * 64 + j * 16 + g * 4 + r > qs + rl) sT[sub][j][r] = -1e30f;
        }
      }

      // per-sub softmax + P round-trip + PV (Ps reused across subs)
#pragma unroll
      for (int sub = 0; sub < 2; ++sub) {
        const int qsub = qsub0 + sub * 16;
        if (kt * 64 > qsub + 15) continue;  // fully-masked sub (last tile only)

        float ps = 0.f;
#pragma unroll
        for (int j = 0; j < 4; ++j) {
          f16x4 pb;
#pragma unroll
          for (int r = 0; r < 4; ++r) {
            float pp = exp2f(sT[sub][j][r]);
            ps += pp;
            pb[r] = (f16)pp;
          }
          *(f16x4*)(&Ps[w][0] + rl * 64 + (((j * 2 + (g >> 1)) ^ (rl & 7)) * 8) + (g & 1) * 4) = pb;
        }
        lrow[sub] += ps;

        asm volatile("s_waitcnt lgkmcnt(0)" ::: "memory");
        __builtin_amdgcn_sched_barrier(0);

        f16x8 pf[2];
#pragma unroll
        for (int ks = 0; ks < 2; ++ks)
          pf[ks] = *(const f16x8*)(&Ps[w][0] + rl * 64 + (((ks * 4 + g) ^ (rl & 7)) * 8));

#pragma unroll
        for (int dj = 0; dj < 4; ++dj)
#pragma unroll
          for (int ks = 0; ks < 2; ++ks) {
            int vrow = dj * 16 + rl;
            f16x8 vf = *(const f16x8*)(Vb + vrow * 64 + (((ks * 4 + g) ^ (rl & 7)) * 8));
            oacc[sub][dj] = mfma16(pf[ks], vf, oacc[sub][dj]);
          }
      }
    }
    __syncthreads();
    buf ^= 1;
  }

  float rinv[2];
#pragma unroll
  for (int sub = 0; sub < 2; ++sub) {
    float s_ = lrow[sub];
    s_ += __shfl_xor(s_, 16, 64);
    s_ += __shfl_xor(s_, 32, 64);
    rinv[sub] = 1.0f / s_;
  }

  const int h = bh & 15;
  const size_t rowb = (size_t)(bh >> 4) * 2048 + qb * 128 + w * 32;
#pragma unroll
  for (int sub = 0; sub < 2; ++sub)
#pragma unroll
    for (int r = 0; r < 4; ++r) {
      float ri = __shfl(rinv[sub], g * 4 + r, 64);
#pragma unroll
      for (int dj = 0; dj < 4; ++dj)
        o[(rowb + sub * 16 + g * 4 + r) * 1024 + h * 64 + dj * 16 + rl] =
            (f16)(oacc[sub][dj][r] * ri);
    }
}

extern "C" void kernel_launch(void* const* d_in, const int* in_sizes, int n_in,
                              void* d_out, int out_size, void* d_ws, size_t ws_size,
                              hipStream_t stream) {
  (void)in_sizes; (void)n_in; (void)out_size; (void)ws_size;
  const float* x    = (const float*)d_in[0];
  const float* wqkv = (const float*)d_in[1];
  const float* bqkv = (const float*)d_in[2];
  const float* wo   = (const float*)d_in[3];
  const float* bo   = (const float*)d_in[4];
  float* out = (float*)d_out;
  char* ws = (char*)d_ws;

  f16* xb    = (f16*)(ws + 0);          // x as f16 [8192][1024]
  f16* wqkvt = (f16*)(ws + 16777216);   // qkv_w^T f16 [3072][1024]
  f16* wot   = (f16*)(ws + 23068672);   // out_w^T f16 [1024][1024]
  f16* qws   = (f16*)(ws + 25165824);   // Q (pre-scaled 0.125*log2e)
  f16* kws   = (f16*)(ws + 41943040);   // K
  f16* vtws  = (f16*)(ws + 58720256);   // V^T
  f16* attnb = xb;

  k_cvt<<<2048, 256, 0, stream>>>(x, xb, 8388608 / 4);
  k_tconv<<<dim3(96, 32), dim3(32, 8), 0, stream>>>(wqkv, wqkvt, 1024, 3072);
  k_tconv<<<dim3(32, 32), dim3(32, 8), 0, stream>>>(wo, wot, 1024, 1024);
  k_gemm_qkv4<<<dim3(12, 64), 256, 0, stream>>>(xb, wqkvt, bqkv, qws, kws, vtws);
  k_attn5<<<1024, 256, 0, stream>>>(qws, kws, vtws, attnb);
  k_gemm_out4<<<dim3(4, 64), 256, 0, stream>>>(attnb, wot, bo, out);
}

// Round 10
// 187.010 us; speedup vs baseline: 1.4581x; 1.0047x over previous
//
#include <hip/hip_runtime.h>

typedef unsigned int u32;
typedef _Float16 f16;
typedef _Float16 f16x8 __attribute__((ext_vector_type(8)));
typedef _Float16 f16x4 __attribute__((ext_vector_type(4)));
typedef float f32x4 __attribute__((ext_vector_type(4)));

#define LOG2E 1.4426950408889634f

__device__ __forceinline__ void gl_lds16(const void* g, void* l) {
  __builtin_amdgcn_global_load_lds(
      (const __attribute__((address_space(1))) u32*)g,
      (__attribute__((address_space(3))) u32*)l, 16, 0, 0);
}

__device__ __forceinline__ f32x4 mfma16(f16x8 a, f16x8 b, f32x4 c) {
  return __builtin_amdgcn_mfma_f32_16x16x32_f16(a, b, c, 0, 0, 0);
}

// ---------------- fp32 -> fp16 convert (16B stores) ----------------
__global__ void k_cvt(const float* __restrict__ in, f16* __restrict__ out, int n8) {
  int stride = gridDim.x * blockDim.x;
  for (int i = blockIdx.x * blockDim.x + threadIdx.x; i < n8; i += stride) {
    f32x4 a = *(const f32x4*)(in + (size_t)i * 8);
    f32x4 b = *(const f32x4*)(in + (size_t)i * 8 + 4);
    f16x8 o;
    o[0] = (f16)a[0]; o[1] = (f16)a[1]; o[2] = (f16)a[2]; o[3] = (f16)a[3];
    o[4] = (f16)b[0]; o[5] = (f16)b[1]; o[6] = (f16)b[2]; o[7] = (f16)b[3];
    *(f16x8*)(out + (size_t)i * 8) = o;
  }
}

// ------------- transpose + convert -------------
__global__ void k_tconv(const float* __restrict__ in, f16* __restrict__ out, int R, int C) {
  __shared__ f16 tile[32][33];
  int c0 = blockIdx.x * 32, r0 = blockIdx.y * 32;
  int tx = threadIdx.x, ty = threadIdx.y;
#pragma unroll
  for (int i = ty; i < 32; i += 8)
    tile[i][tx] = (f16)in[(size_t)(r0 + i) * C + c0 + tx];
  __syncthreads();
#pragma unroll
  for (int i = ty; i < 32; i += 8)
    out[(size_t)(c0 + i) * R + r0 + tx] = tile[tx][i];
}

// ================= m97-clone GEMM core =================
// 128x128 block, 4 waves (2Mx2N), per-wave 64x64 (acc[4][4]=64 AGPR -> ~150 VGPR
// total -> 3 waves/SIMD -> 3 blocks/CU resident). 2x16KB LDS dbuf; per K-tile:
// issue 4 gl_lds for tile t+1 into buf^1, C++ frag reads + 16 MFMA on buf, ONE
// __syncthreads (compiler emits the vmcnt/lgkm waits; m114: multi-block TLP
// hides the drain). Verified-conflict-free XOR slot swizzle (both sides).
__device__ __forceinline__ void gemm97(
    const f16* __restrict__ A, const f16* __restrict__ Bt,
    int bm, int bn, f16* SM, int w, int lane, f32x4 (&acc)[4][4]) {
  constexpr int KT = 32;
  const int g = lane >> 4, rl = lane & 15;
  const int l4 = lane >> 2, ls = lane & 3;
  const int sslot = ls ^ ((l4 >> 1) & 3);
  const int wr = w >> 1, wc = w & 1;

  const f16* aS = A + (size_t)(bm + w * 16 + l4) * 1024 + sslot * 8;
  const f16* bS = Bt + (size_t)(bn + w * 16 + l4) * 1024 + sslot * 8;

#define STG97(b, kt) do { \
    gl_lds16(aS + (kt) * 32,          SM + (b) * 8192 + w * 512); \
    gl_lds16(aS + 65536 + (kt) * 32,  SM + (b) * 8192 + 2048 + w * 512); \
    gl_lds16(bS + (kt) * 32,          SM + (b) * 8192 + 4096 + w * 512); \
    gl_lds16(bS + 65536 + (kt) * 32,  SM + (b) * 8192 + 6144 + w * 512); } while (0)

  const int ro = rl * 32 + ((g ^ ((rl >> 1) & 3)) * 8);

  STG97(0, 0);
  __syncthreads();

#pragma unroll 1
  for (int kt = 0; kt < KT; ++kt) {
    const int cur = kt & 1;
    if (kt + 1 < KT) STG97(cur ^ 1, kt + 1);
    const f16* SMb = SM + cur * 8192;
    f16x8 af[4], bf[4];
#pragma unroll
    for (int mi = 0; mi < 4; ++mi)
      af[mi] = *(const f16x8*)(SMb + wr * 2048 + mi * 512 + ro);
#pragma unroll
    for (int j = 0; j < 4; ++j)
      bf[j] = *(const f16x8*)(SMb + 4096 + wc * 2048 + j * 512 + ro);
    __builtin_amdgcn_s_setprio(1);
#pragma unroll
    for (int mi = 0; mi < 4; ++mi)
#pragma unroll
      for (int j = 0; j < 4; ++j)
        acc[mi][j] = mfma16(af[mi], bf[j], acc[mi][j]);
    __builtin_amdgcn_s_setprio(0);
    __syncthreads();
  }
#undef STG97
}

// ---------------- QKV projection GEMM (m97-clone, 1536 blocks = 2 full rounds) ----------------
__global__ __launch_bounds__(256, 3) void k_gemm_qkv5(
    const f16* __restrict__ A, const f16* __restrict__ Bt,
    const float* __restrict__ bias,
    f16* __restrict__ qo, f16* __restrict__ ko2, f16* __restrict__ vto) {
  __shared__ __align__(16) f16 SM[16384];  // 32 KB -> LDS allows 5, VGPR gives 3 blocks/CU
  const int lin0 = blockIdx.y * 24 + blockIdx.x;     // 1536 blocks
  const int lin = (lin0 & 7) * 192 + (lin0 >> 3);    // XCD-contiguous (1536%8==0)
  const int bn = (lin % 24) * 128, bm = (lin / 24) * 128;
  const int t = threadIdx.x, lane = t & 63, w = t >> 6;
  const int g = lane >> 4, rl = lane & 15;
  const int wr = w >> 1, wc = w & 1;

  f32x4 acc[4][4] = {};
  gemm97(A, Bt, bm, bn, SM, w, lane, acc);

  // epilogue: C row=(lane>>4)*4+reg, col=lane&15; scatter q/k/v
#pragma unroll
  for (int i = 0; i < 4; ++i)
#pragma unroll
    for (int j = 0; j < 4; ++j)
#pragma unroll
      for (int r = 0; r < 4; ++r) {
        int m = bm + wr * 64 + i * 16 + g * 4 + r;
        int n = bn + wc * 64 + j * 16 + rl;
        float v = acc[i][j][r] + bias[n];
        int b = m >> 11, s = m & 2047;
        int h = n / 192, rem = n - h * 192;
        int tsel = rem >> 6, dd = rem & 63;
        size_t bh = (size_t)(b * 16 + h);
        if (tsel == 0)      qo[(bh * 2048 + s) * 64 + dd] = (f16)(v * (0.125f * LOG2E));
        else if (tsel == 1) ko2[(bh * 2048 + s) * 64 + dd] = (f16)v;
        else                vto[(bh * 64 + dd) * 2048 + s] = (f16)v;  // V transposed
      }
}

// ---------------- output projection GEMM (m97-clone, 512 blocks = full pack) ----------------
__global__ __launch_bounds__(256, 3) void k_gemm_out5(
    const f16* __restrict__ A, const f16* __restrict__ Bt,
    const float* __restrict__ bias, float* __restrict__ out) {
  __shared__ __align__(16) f16 SM[16384];
  const int lin0 = blockIdx.y * 8 + blockIdx.x;      // 512 blocks
  const int lin = (lin0 & 7) * 64 + (lin0 >> 3);
  const int bn = (lin % 8) * 128, bm = (lin / 8) * 128;
  const int t = threadIdx.x, lane = t & 63, w = t >> 6;
  const int g = lane >> 4, rl = lane & 15;
  const int wr = w >> 1, wc = w & 1;

  f32x4 acc[4][4] = {};
  gemm97(A, Bt, bm, bn, SM, w, lane, acc);

#pragma unroll
  for (int i = 0; i < 4; ++i)
#pragma unroll
    for (int j = 0; j < 4; ++j)
#pragma unroll
      for (int r = 0; r < 4; ++r) {
        int m = bm + wr * 64 + i * 16 + g * 4 + r;
        int n = bn + wc * 64 + j * 16 + rl;
        out[(size_t)m * 1024 + n] = acc[i][j][r] + bias[n];
      }
}

// ---------------- flash attention v5 (unchanged from round 9) ----------------
__global__ __launch_bounds__(256, 4) void k_attn5(
    const f16* __restrict__ q, const f16* __restrict__ kgl,
    const f16* __restrict__ vt, f16* __restrict__ o) {
  constexpr int S = 2048;
  __shared__ __align__(16) f16 Ks[2][64 * 64];
  __shared__ __align__(16) f16 Vs[2][64 * 64];
  __shared__ __align__(16) f16 Ps[4][16 * 64];

  const int d = blockIdx.x;
  const int bh = (d & 7) * 8 + ((d >> 3) & 7);  // XCD i owns bh [8i,8i+8)
  const int v_ = d >> 6, g2 = v_ >> 2, r2 = v_ & 3;
  const int qb = (g2 == 0) ? 15 - r2 : (g2 == 1) ? r2 : (g2 == 2) ? 11 - r2 : 4 + r2;

  const int t = threadIdx.x, lane = t & 63, w = t >> 6;
  const int g = lane >> 4, rl = lane & 15;

  const f16* qp = q + ((size_t)bh * S + qb * 128) * 64;
  const f16* kb = kgl + (size_t)bh * S * 64;
  const f16* vb = vt + (size_t)bh * 64 * S;

  f16x8 qf[2][2];
#pragma unroll
  for (int sub = 0; sub < 2; ++sub)
#pragma unroll
    for (int ks = 0; ks < 2; ++ks)
      qf[sub][ks] = *(const f16x8*)(qp + (size_t)(w * 32 + sub * 16 + rl) * 64 + ks * 32 + g * 8);

  f32x4 oacc[2][4] = {};
  float lrow[2] = {0.f, 0.f};

  const int srow = lane >> 3;
  const int sslot = (lane & 7) ^ srow;

  const int nkt = 2 * qb + 2;
  const int qsub0 = qb * 128 + w * 32;
  const int qmaxw = qsub0 + 31;

  auto STAGE = [&](int bufi, int kt) {
#pragma unroll
    for (int i = 0; i < 2; ++i) {
      const int r0 = w * 16 + i * 8;
      gl_lds16(kb + (size_t)(kt * 64 + r0 + srow) * 64 + sslot * 8, &Ks[bufi][r0 * 64]);
      gl_lds16(vb + (size_t)(r0 + srow) * S + kt * 64 + sslot * 8, &Vs[bufi][r0 * 64]);
    }
  };

  STAGE(0, 0);
  __syncthreads();
  int buf = 0;

  for (int kt = 0; kt < nkt; ++kt) {
    if (kt + 1 < nkt) STAGE(buf ^ 1, kt + 1);

    if (kt * 64 <= qmaxw) {
      const f16* Kb = &Ks[buf][0];
      const f16* Vb = &Vs[buf][0];

      f32x4 sT[2][4] = {};
#pragma unroll
      for (int j = 0; j < 4; ++j)
#pragma unroll
        for (int ks = 0; ks < 2; ++ks) {
          int row = j * 16 + rl;
          f16x8 kf = *(const f16x8*)(Kb + row * 64 + (((ks * 4 + g) ^ (rl & 7)) * 8));
          sT[0][j] = mfma16(kf, qf[0][ks], sT[0][j]);
          sT[1][j] = mfma16(kf, qf[1][ks], sT[1][j]);
        }

      if (kt * 64 + 63 > qsub0) {
#pragma unroll
        for (int sub = 0; sub < 2; ++sub) {
          const int qs = qsub0 + sub * 16;
#pragma unroll
          for (int j = 0; j < 4; ++j)
#pragma unroll
            for (int r = 0; r < 4; ++r)
              if (kt * 64 + j * 16 + g * 4 + r > qs + rl) sT[sub][j][r] = -1e30f;
        }
      }

#pragma unroll
      for (int sub = 0; sub < 2; ++sub) {
        const int qsub = qsub0 + sub * 16;
        if (kt * 64 > qsub + 15) continue;

        float ps = 0.f;
#pragma unroll
        for (int j = 0; j < 4; ++j) {
          f16x4 pb;
#pragma unroll
          for (int r = 0; r < 4; ++r) {
            float pp = exp2f(sT[sub][j][r]);
            ps += pp;
            pb[r] = (f16)pp;
          }
          *(f16x4*)(&Ps[w][0] + rl * 64 + (((j * 2 + (g >> 1)) ^ (rl & 7)) * 8) + (g & 1) * 4) = pb;
        }
        lrow[sub] += ps;

        asm volatile("s_waitcnt lgkmcnt(0)" ::: "memory");
        __builtin_amdgcn_sched_barrier(0);

        f16x8 pf[2];
#pragma unroll
        for (int ks = 0; ks < 2; ++ks)
          pf[ks] = *(const f16x8*)(&Ps[w][0] + rl * 64 + (((ks * 4 + g) ^ (rl & 7)) * 8));

#pragma unroll
        for (int dj = 0; dj < 4; ++dj)
#pragma unroll
          for (int ks = 0; ks < 2; ++ks) {
            int vrow = dj * 16 + rl;
            f16x8 vf = *(const f16x8*)(Vb + vrow * 64 + (((ks * 4 + g) ^ (rl & 7)) * 8));
            oacc[sub][dj] = mfma16(pf[ks], vf, oacc[sub][dj]);
          }
      }
    }
    __syncthreads();
    buf ^= 1;
  }

  float rinv[2];
#pragma unroll
  for (int sub = 0; sub < 2; ++sub) {
    float s_ = lrow[sub];
    s_ += __shfl_xor(s_, 16, 64);
    s_ += __shfl_xor(s_, 32, 64);
    rinv[sub] = 1.0f / s_;
  }

  const int h = bh & 15;
  const size_t rowb = (size_t)(bh >> 4) * 2048 + qb * 128 + w * 32;
#pragma unroll
  for (int sub = 0; sub < 2; ++sub)
#pragma unroll
    for (int r = 0; r < 4; ++r) {
      float ri = __shfl(rinv[sub], g * 4 + r, 64);
#pragma unroll
      for (int dj = 0; dj < 4; ++dj)
        o[(rowb + sub * 16 + g * 4 + r) * 1024 + h * 64 + dj * 16 + rl] =
            (f16)(oacc[sub][dj][r] * ri);
    }
}

extern "C" void kernel_launch(void* const* d_in, const int* in_sizes, int n_in,
                              void* d_out, int out_size, void* d_ws, size_t ws_size,
                              hipStream_t stream) {
  (void)in_sizes; (void)n_in; (void)out_size; (void)ws_size;
  const float* x    = (const float*)d_in[0];
  const float* wqkv = (const float*)d_in[1];
  const float* bqkv = (const float*)d_in[2];
  const float* wo   = (const float*)d_in[3];
  const float* bo   = (const float*)d_in[4];
  float* out = (float*)d_out;
  char* ws = (char*)d_ws;

  f16* xb    = (f16*)(ws + 0);          // x as f16 [8192][1024]
  f16* wqkvt = (f16*)(ws + 16777216);   // qkv_w^T f16 [3072][1024]
  f16* wot   = (f16*)(ws + 23068672);   // out_w^T f16 [1024][1024]
  f16* qws   = (f16*)(ws + 25165824);   // Q (pre-scaled 0.125*log2e)
  f16* kws   = (f16*)(ws + 41943040);   // K
  f16* vtws  = (f16*)(ws + 58720256);   // V^T
  f16* attnb = xb;

  k_cvt<<<1024, 256, 0, stream>>>(x, xb, 8388608 / 8);
  k_tconv<<<dim3(96, 32), dim3(32, 8), 0, stream>>>(wqkv, wqkvt, 1024, 3072);
  k_tconv<<<dim3(32, 32), dim3(32, 8), 0, stream>>>(wo, wot, 1024, 1024);
  k_gemm_qkv5<<<dim3(24, 64), 256, 0, stream>>>(xb, wqkvt, bqkv, qws, kws, vtws);
  k_attn5<<<1024, 256, 0, stream>>>(qws, kws, vtws, attnb);
  k_gemm_out5<<<dim3(8, 64), 256, 0, stream>>>(attnb, wot, bo, out);
}

// Round 12
// 184.129 us; speedup vs baseline: 1.4809x; 1.0156x over previous
//
#include <hip/hip_runtime.h>

typedef unsigned int u32;
typedef _Float16 f16;
typedef _Float16 f16x8 __attribute__((ext_vector_type(8)));
typedef _Float16 f16x4 __attribute__((ext_vector_type(4)));
typedef float f32x4 __attribute__((ext_vector_type(4)));
typedef _Float16 __attribute__((address_space(3))) lf16;

#define LOG2E 1.4426950408889634f

__device__ __forceinline__ void gl_lds16(const void* g, void* l) {
  __builtin_amdgcn_global_load_lds(
      (const __attribute__((address_space(1))) u32*)g,
      (__attribute__((address_space(3))) u32*)l, 16, 0, 0);
}

__device__ __forceinline__ f32x4 mfma16(f16x8 a, f16x8 b, f32x4 c) {
  return __builtin_amdgcn_mfma_f32_16x16x32_f16(a, b, c, 0, 0, 0);
}

// inline-asm LDS read: compiler cannot see the op -> cannot insert conservative
// vmcnt drains against outstanding global_load_lds; we fence per rule #18.
__device__ __forceinline__ f16x8 ldsr(const f16* p) {
  f16x8 r;
  asm volatile("ds_read_b128 %0, %1" : "=v"(r) : "v"((const lf16*)p));
  return r;
}

// ---------------- fp32 -> fp16 convert (16B stores) ----------------
__global__ void k_cvt(const float* __restrict__ in, f16* __restrict__ out, int n8) {
  int stride = gridDim.x * blockDim.x;
  for (int i = blockIdx.x * blockDim.x + threadIdx.x; i < n8; i += stride) {
    f32x4 a = *(const f32x4*)(in + (size_t)i * 8);
    f32x4 b = *(const f32x4*)(in + (size_t)i * 8 + 4);
    f16x8 o;
    o[0] = (f16)a[0]; o[1] = (f16)a[1]; o[2] = (f16)a[2]; o[3] = (f16)a[3];
    o[4] = (f16)b[0]; o[5] = (f16)b[1]; o[6] = (f16)b[2]; o[7] = (f16)b[3];
    *(f16x8*)(out + (size_t)i * 8) = o;
  }
}

// ------------- transpose + convert -------------
__global__ void k_tconv(const float* __restrict__ in, f16* __restrict__ out, int R, int C) {
  __shared__ f16 tile[32][33];
  int c0 = blockIdx.x * 32, r0 = blockIdx.y * 32;
  int tx = threadIdx.x, ty = threadIdx.y;
#pragma unroll
  for (int i = ty; i < 32; i += 8)
    tile[i][tx] = (f16)in[(size_t)(r0 + i) * C + c0 + tx];
  __syncthreads();
#pragma unroll
  for (int i = ty; i < 32; i += 8)
    out[(size_t)(c0 + i) * R + r0 + tx] = tile[tx][i];
}

// ================= fat-wave core, ASM LDS reads (round-9 best: 659 TF) =================
__device__ __forceinline__ void gemm_fatA(
    const f16* __restrict__ A, const f16* __restrict__ Bt,
    int bm, int bn, f16* SM, int w, int lane, f32x4 (&acc)[8][4]) {
  constexpr int KT = 32;
  const int g = lane >> 4, rl = lane & 15;
  const int l4 = lane >> 2, ls = lane & 3;
  const int sslot = ls ^ ((l4 >> 1) & 3);

  const f16* aS = A + (size_t)(bm + w * 32 + l4) * 1024 + sslot * 8;
  const f16* bS = Bt + (size_t)(bn + w * 16 + l4) * 1024 + sslot * 8;
  f16* aD = SM + w * 1024;
  f16* bD = SM + 4096 + w * 512;

#define ASTG0(b, kt) do { \
    gl_lds16(aS + (kt) * 32,          aD + (b) * 12288); \
    gl_lds16(aS + 16384 + (kt) * 32,  aD + (b) * 12288 + 512); \
    gl_lds16(bS + (kt) * 32,          bD + (b) * 12288); } while (0)
#define ASTG1(b, kt) do { \
    gl_lds16(bS + 65536 + (kt) * 32,  bD + (b) * 12288 + 2048); \
    gl_lds16(bS + 131072 + (kt) * 32, bD + (b) * 12288 + 4096); \
    gl_lds16(bS + 196608 + (kt) * 32, bD + (b) * 12288 + 6144); } while (0)

  ASTG0(0, 0); ASTG1(0, 0);
  ASTG0(1, 1); ASTG1(1, 1);
  asm volatile("s_waitcnt vmcnt(6)" ::: "memory");
  __builtin_amdgcn_s_barrier();

  const int ro = rl * 32 + ((g ^ ((rl >> 1) & 3)) * 8);

  int c = 0, cs = 2;
#pragma unroll 1
  for (int kt = 0; kt < KT; ++kt) {
    const f16* SMc = SM + c * 12288;
    const bool stg = (kt + 2 < KT);
    f16x8 bf[4], af[4];

    {
#pragma unroll
      for (int j = 0; j < 4; ++j)
        bf[j] = ldsr(SMc + 4096 + w * 2048 + j * 512 + ro);
#pragma unroll
      for (int mi = 0; mi < 4; ++mi)
        af[mi] = ldsr(SMc + mi * 512 + ro);
      if (stg) ASTG0(cs, kt + 2);
      __builtin_amdgcn_s_barrier();
      asm volatile("s_waitcnt lgkmcnt(0)");
      __builtin_amdgcn_sched_barrier(0);
      __builtin_amdgcn_s_setprio(1);
#pragma unroll
      for (int mi = 0; mi < 4; ++mi)
#pragma unroll
        for (int j = 0; j < 4; ++j)
          acc[mi][j] = mfma16(af[mi], bf[j], acc[mi][j]);
      __builtin_amdgcn_s_setprio(0);
      __builtin_amdgcn_sched_barrier(0);
      __builtin_amdgcn_s_barrier();
    }
    {
#pragma unroll
      for (int mi = 0; mi < 4; ++mi)
        af[mi] = ldsr(SMc + (4 + mi) * 512 + ro);
      if (stg) ASTG1(cs, kt + 2);
      __builtin_amdgcn_s_barrier();
      asm volatile("s_waitcnt lgkmcnt(0)");
      __builtin_amdgcn_sched_barrier(0);
      __builtin_amdgcn_s_setprio(1);
#pragma unroll
      for (int mi = 0; mi < 4; ++mi)
#pragma unroll
        for (int j = 0; j < 4; ++j)
          acc[4 + mi][j] = mfma16(af[mi], bf[j], acc[4 + mi][j]);
      __builtin_amdgcn_s_setprio(0);
      __builtin_amdgcn_sched_barrier(0);
      if (kt + 2 < KT)      { asm volatile("s_waitcnt vmcnt(6)" ::: "memory"); }
      else if (kt + 1 < KT) { asm volatile("s_waitcnt vmcnt(0)" ::: "memory"); }
      __builtin_amdgcn_s_barrier();
      __builtin_amdgcn_sched_barrier(0);
    }
    c = (c == 2) ? 0 : c + 1;
    cs = (cs == 2) ? 0 : cs + 1;
  }
#undef ASTG0
#undef ASTG1
}

// ---------------- QKV projection GEMM (asm-read fat-wave, round-9 best) ----------------
__global__ __launch_bounds__(256, 2) void k_gemm_qkv4(
    const f16* __restrict__ A, const f16* __restrict__ Bt,
    const float* __restrict__ bias,
    f16* __restrict__ qo, f16* __restrict__ ko2, f16* __restrict__ vto) {
  __shared__ __align__(16) f16 SM[36864];
  const int lin0 = blockIdx.y * 12 + blockIdx.x;
  const int lin = (lin0 & 7) * 96 + (lin0 >> 3);
  const int bn = (lin % 12) * 256, bm = (lin / 12) * 128;
  const int t = threadIdx.x, lane = t & 63, w = t >> 6;
  const int g = lane >> 4, rl = lane & 15;

  f32x4 acc[8][4] = {};
  gemm_fatA(A, Bt, bm, bn, SM, w, lane, acc);

#pragma unroll
  for (int mi = 0; mi < 8; ++mi)
#pragma unroll
    for (int j = 0; j < 4; ++j)
#pragma unroll
      for (int r = 0; r < 4; ++r) {
        int m = bm + mi * 16 + g * 4 + r;
        int n = bn + w * 64 + j * 16 + rl;
        float v = acc[mi][j][r] + bias[n];
        int b = m >> 11, s = m & 2047;
        int h = n / 192, rem = n - h * 192;
        int tsel = rem >> 6, dd = rem & 63;
        size_t bh = (size_t)(b * 16 + h);
        if (tsel == 0)      qo[(bh * 2048 + s) * 64 + dd] = (f16)(v * (0.125f * LOG2E));
        else if (tsel == 1) ko2[(bh * 2048 + s) * 64 + dd] = (f16)v;
        else                vto[(bh * 64 + dd) * 2048 + s] = (f16)v;
      }
}

// ================= m97-clone core (out GEMM: best packing at 512 blocks) =================
__device__ __forceinline__ void gemm97(
    const f16* __restrict__ A, const f16* __restrict__ Bt,
    int bm, int bn, f16* SM, int w, int lane, f32x4 (&acc)[4][4]) {
  constexpr int KT = 32;
  const int g = lane >> 4, rl = lane & 15;
  const int l4 = lane >> 2, ls = lane & 3;
  const int sslot = ls ^ ((l4 >> 1) & 3);
  const int wr = w >> 1, wc = w & 1;

  const f16* aS = A + (size_t)(bm + w * 16 + l4) * 1024 + sslot * 8;
  const f16* bS = Bt + (size_t)(bn + w * 16 + l4) * 1024 + sslot * 8;

#define STG97(b, kt) do { \
    gl_lds16(aS + (kt) * 32,          SM + (b) * 8192 + w * 512); \
    gl_lds16(aS + 65536 + (kt) * 32,  SM + (b) * 8192 + 2048 + w * 512); \
    gl_lds16(bS + (kt) * 32,          SM + (b) * 8192 + 4096 + w * 512); \
    gl_lds16(bS + 65536 + (kt) * 32,  SM + (b) * 8192 + 6144 + w * 512); } while (0)

  const int ro = rl * 32 + ((g ^ ((rl >> 1) & 3)) * 8);

  STG97(0, 0);
  __syncthreads();

#pragma unroll 1
  for (int kt = 0; kt < KT; ++kt) {
    const int cur = kt & 1;
    if (kt + 1 < KT) STG97(cur ^ 1, kt + 1);
    const f16* SMb = SM + cur * 8192;
    f16x8 af[4], bf[4];
#pragma unroll
    for (int mi = 0; mi < 4; ++mi)
      af[mi] = *(const f16x8*)(SMb + wr * 2048 + mi * 512 + ro);
#pragma unroll
    for (int j = 0; j < 4; ++j)
      bf[j] = *(const f16x8*)(SMb + 4096 + wc * 2048 + j * 512 + ro);
    __builtin_amdgcn_s_setprio(1);
#pragma unroll
    for (int mi = 0; mi < 4; ++mi)
#pragma unroll
      for (int j = 0; j < 4; ++j)
        acc[mi][j] = mfma16(af[mi], bf[j], acc[mi][j]);
    __builtin_amdgcn_s_setprio(0);
    __syncthreads();
  }
#undef STG97
}

// ---------------- output projection GEMM (m97-clone, 512 blocks full pack) ----------------
__global__ __launch_bounds__(256, 3) void k_gemm_out5(
    const f16* __restrict__ A, const f16* __restrict__ Bt,
    const float* __restrict__ bias, float* __restrict__ out) {
  __shared__ __align__(16) f16 SM[16384];
  const int lin0 = blockIdx.y * 8 + blockIdx.x;      // 512 blocks
  const int lin = (lin0 & 7) * 64 + (lin0 >> 3);
  const int bn = (lin % 8) * 128, bm = (lin / 8) * 128;
  const int t = threadIdx.x, lane = t & 63, w = t >> 6;
  const int g = lane >> 4, rl = lane & 15;
  const int wr = w >> 1, wc = w & 1;

  f32x4 acc[4][4] = {};
  gemm97(A, Bt, bm, bn, SM, w, lane, acc);

#pragma unroll
  for (int i = 0; i < 4; ++i)
#pragma unroll
    for (int j = 0; j < 4; ++j)
#pragma unroll
      for (int r = 0; r < 4; ++r) {
        int m = bm + wr * 64 + i * 16 + g * 4 + r;
        int n = bn + wc * 64 + j * 16 + rl;
        out[(size_t)m * 1024 + n] = acc[i][j][r] + bias[n];
      }
}

// ---------------- flash attention v6 ----------------
// attn5 + merged PV (one vf load feeds both subs: -8 b128/tile), cvt_pkrtz
// packing, setprio on MFMA clusters. Both subs always active when the outer
// guard passes (strips are 64-aligned), so merged PV needs no per-sub guard.
__global__ __launch_bounds__(256, 4) void k_attn6(
    const f16* __restrict__ q, const f16* __restrict__ kgl,
    const f16* __restrict__ vt, f16* __restrict__ o) {
  constexpr int S = 2048;
  __shared__ __align__(16) f16 Ks[2][64 * 64];
  __shared__ __align__(16) f16 Vs[2][64 * 64];
  __shared__ __align__(16) f16 Ps[4][16 * 64];

  const int d = blockIdx.x;
  const int bh = (d & 7) * 8 + ((d >> 3) & 7);  // XCD i owns bh [8i,8i+8)
  const int v_ = d >> 6, g2 = v_ >> 2, r2 = v_ & 3;
  const int qb = (g2 == 0) ? 15 - r2 : (g2 == 1) ? r2 : (g2 == 2) ? 11 - r2 : 4 + r2;

  const int t = threadIdx.x, lane = t & 63, w = t >> 6;
  const int g = lane >> 4, rl = lane & 15;

  const f16* qp = q + ((size_t)bh * S + qb * 128) * 64;
  const f16* kb = kgl + (size_t)bh * S * 64;
  const f16* vb = vt + (size_t)bh * 64 * S;

  f16x8 qf[2][2];
#pragma unroll
  for (int sub = 0; sub < 2; ++sub)
#pragma unroll
    for (int ks = 0; ks < 2; ++ks)
      qf[sub][ks] = *(const f16x8*)(qp + (size_t)(w * 32 + sub * 16 + rl) * 64 + ks * 32 + g * 8);

  f32x4 oacc[2][4] = {};
  float lrow[2] = {0.f, 0.f};

  const int srow = lane >> 3;
  const int sslot = (lane & 7) ^ srow;

  const int nkt = 2 * qb + 2;
  const int qsub0 = qb * 128 + w * 32;
  const int qmaxw = qsub0 + 31;

  auto STAGE = [&](int bufi, int kt) {
#pragma unroll
    for (int i = 0; i < 2; ++i) {
      const int r0 = w * 16 + i * 8;
      gl_lds16(kb + (size_t)(kt * 64 + r0 + srow) * 64 + sslot * 8, &Ks[bufi][r0 * 64]);
      gl_lds16(vb + (size_t)(r0 + srow) * S + kt * 64 + sslot * 8, &Vs[bufi][r0 * 64]);
    }
  };

  STAGE(0, 0);
  __syncthreads();
  int buf = 0;

  for (int kt = 0; kt < nkt; ++kt) {
    if (kt + 1 < nkt) STAGE(buf ^ 1, kt + 1);

    if (kt * 64 <= qmaxw) {
      const f16* Kb = &Ks[buf][0];
      const f16* Vb = &Vs[buf][0];

      // merged QK^T: each K-fragment feeds both subs
      f32x4 sT[2][4] = {};
      __builtin_amdgcn_s_setprio(1);
#pragma unroll
      for (int j = 0; j < 4; ++j)
#pragma unroll
        for (int ks = 0; ks < 2; ++ks) {
          int row = j * 16 + rl;
          f16x8 kf = *(const f16x8*)(Kb + row * 64 + (((ks * 4 + g) ^ (rl & 7)) * 8));
          sT[0][j] = mfma16(kf, qf[0][ks], sT[0][j]);
          sT[1][j] = mfma16(kf, qf[1][ks], sT[1][j]);
        }
      __builtin_amdgcn_s_setprio(0);

      if (kt * 64 + 63 > qsub0) {  // boundary: causal mask both subs
#pragma unroll
        for (int sub = 0; sub < 2; ++sub) {
          const int qs = qsub0 + sub * 16;
#pragma unroll
          for (int j = 0; j < 4; ++j)
#pragma unroll
            for (int r = 0; r < 4; ++r)
              if (kt * 64 + j * 16 + g * 4 + r > qs + rl) sT[sub][j][r] = -1e30f;
        }
      }

      // per-sub softmax through wave-private LDS; pf kept for merged PV
      f16x8 pf[2][2];
#pragma unroll
      for (int sub = 0; sub < 2; ++sub) {
        float ps = 0.f;
#pragma unroll
        for (int j = 0; j < 4; ++j) {
          float p0 = exp2f(sT[sub][j][0]);
          float p1 = exp2f(sT[sub][j][1]);
          float p2 = exp2f(sT[sub][j][2]);
          float p3 = exp2f(sT[sub][j][3]);
          ps += (p0 + p1) + (p2 + p3);
          auto lo = __builtin_amdgcn_cvt_pkrtz(p0, p1);
          auto hi = __builtin_amdgcn_cvt_pkrtz(p2, p3);
          f16x4 pb;
          pb[0] = (f16)lo[0]; pb[1] = (f16)lo[1]; pb[2] = (f16)hi[0]; pb[3] = (f16)hi[1];
          *(f16x4*)(&Ps[w][0] + rl * 64 + (((j * 2 + (g >> 1)) ^ (rl & 7)) * 8) + (g & 1) * 4) = pb;
        }
        lrow[sub] += ps;

        asm volatile("s_waitcnt lgkmcnt(0)" ::: "memory");
        __builtin_amdgcn_sched_barrier(0);

#pragma unroll
        for (int ks = 0; ks < 2; ++ks)
          pf[sub][ks] = *(const f16x8*)(&Ps[w][0] + rl * 64 + (((ks * 4 + g) ^ (rl & 7)) * 8));
      }

      // merged PV: one vf load feeds both subs
      __builtin_amdgcn_s_setprio(1);
#pragma unroll
      for (int dj = 0; dj < 4; ++dj)
#pragma unroll
        for (int ks = 0; ks < 2; ++ks) {
          int vrow = dj * 16 + rl;
          f16x8 vf = *(const f16x8*)(Vb + vrow * 64 + (((ks * 4 + g) ^ (rl & 7)) * 8));
          oacc[0][dj] = mfma16(pf[0][ks], vf, oacc[0][dj]);
          oacc[1][dj] = mfma16(pf[1][ks], vf, oacc[1][dj]);
        }
      __builtin_amdgcn_s_setprio(0);
    }
    __syncthreads();
    buf ^= 1;
  }

  float rinv[2];
#pragma unroll
  for (int sub = 0; sub < 2; ++sub) {
    float s_ = lrow[sub];
    s_ += __shfl_xor(s_, 16, 64);
    s_ += __shfl_xor(s_, 32, 64);
    rinv[sub] = 1.0f / s_;
  }

  const int h = bh & 15;
  const size_t rowb = (size_t)(bh >> 4) * 2048 + qb * 128 + w * 32;
#pragma unroll
  for (int sub = 0; sub < 2; ++sub)
#pragma unroll
    for (int r = 0; r < 4; ++r) {
      float ri = __shfl(rinv[sub], g * 4 + r, 64);
#pragma unroll
      for (int dj = 0; dj < 4; ++dj)
        o[(rowb + sub * 16 + g * 4 + r) * 1024 + h * 64 + dj * 16 + rl] =
            (f16)(oacc[sub][dj][r] * ri);
    }
}

extern "C" void kernel_launch(void* const* d_in, const int* in_sizes, int n_in,
                              void* d_out, int out_size, void* d_ws, size_t ws_size,
                              hipStream_t stream) {
  (void)in_sizes; (void)n_in; (void)out_size; (void)ws_size;
  const float* x    = (const float*)d_in[0];
  const float* wqkv = (const float*)d_in[1];
  const float* bqkv = (const float*)d_in[2];
  const float* wo   = (const float*)d_in[3];
  const float* bo   = (const float*)d_in[4];
  float* out = (float*)d_out;
  char* ws = (char*)d_ws;

  f16* xb    = (f16*)(ws + 0);          // x as f16 [8192][1024]
  f16* wqkvt = (f16*)(ws + 16777216);   // qkv_w^T f16 [3072][1024]
  f16* wot   = (f16*)(ws + 23068672);   // out_w^T f16 [1024][1024]
  f16* qws   = (f16*)(ws + 25165824);   // Q (pre-scaled 0.125*log2e)
  f16* kws   = (f16*)(ws + 41943040);   // K
  f16* vtws  = (f16*)(ws + 58720256);   // V^T
  f16* attnb = xb;

  k_cvt<<<1024, 256, 0, stream>>>(x, xb, 8388608 / 8);
  k_tconv<<<dim3(96, 32), dim3(32, 8), 0, stream>>>(wqkv, wqkvt, 1024, 3072);
  k_tconv<<<dim3(32, 32), dim3(32, 8), 0, stream>>>(wo, wot, 1024, 1024);
  k_gemm_qkv4<<<dim3(12, 64), 256, 0, stream>>>(xb, wqkvt, bqkv, qws, kws, vtws);
  k_attn6<<<1024, 256, 0, stream>>>(qws, kws, vtws, attnb);
  k_gemm_out5<<<dim3(8, 64), 256, 0, stream>>>(attnb, wot, bo, out);
}